// Round 4
// baseline (970.286 us; speedup 1.0000x reference)
//
#include <hip/hip_runtime.h>
#include <hip/hip_bf16.h>

#define NN 50000
#define NE 800000
#define INC 64
#define HC 128
#define NC1 64
#define NC2 16

// ---- workspace layout (float offsets) ----
#define OFF_FLAG 0
#define OFW_W1R 16
#define OFW_W1O 8208
#define OFW_B1  16400
#define OFW_PW1 16528
#define OFW_PB1 24720
#define OFW_G1  24784
#define OFW_BE1 24848
#define OFW_W2R 24912
#define OFW_B2  41296
#define OFW_W2O 41424
#define OFW_PW2 57808
#define OFW_PB2 59856
#define OFW_G2  59872
#define OFW_BE2 59888
#define CVT_TOTAL 59888

#define OFF_MG   59904
#define OFF_MTG  64000
#define OFF_DEG2 68096
#define OFF_S2G  68160
#define OFF_ROFF 69184
#define OFF_COFF 119188
#define OFF_BSUM 169192
#define OFF_XD   169592
#define OFF_X1   3369592
#define OFF_S    9769592
#define OFF_AGG  12969592
#define OFF_CSRC 16169592
#define OFF_RDST 16969592
// ---- zero region ----
#define OFF_SCAL 17769592
#define OFF_PX   17769608
#define OFF_PADJ 17777800
#define OFF_STS  17781896
#define OFF_CNT  17785992
#define OFF_CUR  17885992
#define OFF_END  17985992
#define ZERO_FLOATS (OFF_END - OFF_SCAL)

__device__ inline float wave_sum(float v){
#pragma unroll
  for (int o = 32; o > 0; o >>= 1) v += __shfl_xor(v, o, 64);
  return v;
}
__device__ inline float wave_max(float v){
#pragma unroll
  for (int o = 32; o > 0; o >>= 1) v = fmaxf(v, __shfl_xor(v, o, 64));
  return v;
}

__device__ inline void store_out(void* out, long long idx, float v, bool bf){
  if (bf) ((__hip_bfloat16*)out)[idx] = __float2bfloat16(v);
  else    ((float*)out)[idx] = v;
}

__device__ inline float block_reduce_256(float v, float* red, int t){
  red[t] = v; __syncthreads();
#pragma unroll
  for (int sh = 128; sh > 0; sh >>= 1){
    if (t < sh) red[t] += red[t + sh];
    __syncthreads();
  }
  float r = red[0];
  __syncthreads();
  return r;
}

// K0: detect input float dtype from drop_mask bit patterns.
__global__ void k_detect(const unsigned int* __restrict__ dmw, float* __restrict__ flag){
  __shared__ int cnt;
  if (threadIdx.x == 0) cnt = 0;
  __syncthreads();
  int c = 0;
  for (int i = threadIdx.x; i < 12288; i += 256){
    unsigned int w = dmw[i];
    if (w == 0x3F803F80u || w == 0x00003F80u) c++;
  }
  atomicAdd(&cnt, c);
  __syncthreads();
  if (threadIdx.x == 0) flag[0] = (cnt > 64) ? 1.0f : 0.0f;  // 1.0 => bf16 inputs
}

// K0b: convert all weight tensors to fp32 in ws (dst = 16 + i)
__global__ void k_cvt(const void* p0, const void* p1, const void* p2, const void* p3,
                      const void* p4, const void* p5, const void* p6, const void* p7,
                      const void* p8, const void* p9, const void* p10, const void* p11,
                      const void* p12, const void* p13,
                      const float* __restrict__ flag, float* __restrict__ ws){
  int i = blockIdx.x * blockDim.x + threadIdx.x;
  if (i >= CVT_TOTAL) return;
  const void* src; int off;
  if      (i < 8192 ){ src = p0;  off = i; }
  else if (i < 16384){ src = p1;  off = i - 8192; }
  else if (i < 16512){ src = p2;  off = i - 16384; }
  else if (i < 24704){ src = p3;  off = i - 16512; }
  else if (i < 24768){ src = p4;  off = i - 24704; }
  else if (i < 24832){ src = p5;  off = i - 24768; }
  else if (i < 24896){ src = p6;  off = i - 24832; }
  else if (i < 41280){ src = p7;  off = i - 24896; }
  else if (i < 41408){ src = p8;  off = i - 41280; }
  else if (i < 57792){ src = p9;  off = i - 41408; }
  else if (i < 59840){ src = p10; off = i - 57792; }
  else if (i < 59856){ src = p11; off = i - 59840; }
  else if (i < 59872){ src = p12; off = i - 59856; }
  else               { src = p13; off = i - 59872; }
  float v = (flag[0] > 0.5f) ? __bfloat162float(((const __hip_bfloat16*)src)[off])
                             : ((const float*)src)[off];
  ws[16 + i] = v;
}

// K1: x_drop = drop_mask[:,None] * x  -> fp32
__global__ void k_xdrop(const void* __restrict__ xr, const void* __restrict__ dmr,
                        const float* __restrict__ flag, float* __restrict__ xd){
  int i = blockIdx.x * blockDim.x + threadIdx.x;
  if (i >= NN * INC) return;
  int n = i >> 6;
  float xv, dv;
  if (flag[0] > 0.5f){
    xv = __bfloat162float(((const __hip_bfloat16*)xr)[i]);
    dv = __bfloat162float(((const __hip_bfloat16*)dmr)[n]);
  } else {
    xv = ((const float*)xr)[i];
    dv = ((const float*)dmr)[n];
  }
  xd[i] = xv * dv;
}

// ---- CSR build ----
__global__ void k_hist(const int* __restrict__ ei, int* __restrict__ cnt){
  int e = blockIdx.x * blockDim.x + threadIdx.x;
  if (e < NE){
    atomicAdd(&cnt[ei[e]], 1);            // row
    atomicAdd(&cnt[NN + ei[NE + e]], 1);  // col
  }
}

__global__ __launch_bounds__(256) void k_scanA(const int* __restrict__ cnt,
                                               int* __restrict__ bsum){
  __shared__ int red[256];
  int b = blockIdx.x;          // 0..391
  int arr = b / 196, ib = b % 196;
  int i = ib * 256 + threadIdx.x;
  int v = (i < NN) ? cnt[arr * NN + i] : 0;
  red[threadIdx.x] = v; __syncthreads();
#pragma unroll
  for (int sh = 128; sh > 0; sh >>= 1){
    if (threadIdx.x < sh) red[threadIdx.x] += red[threadIdx.x + sh];
    __syncthreads();
  }
  if (threadIdx.x == 0) bsum[b] = red[0];
}

__global__ __launch_bounds__(256) void k_scanB(int* __restrict__ bsum,
                                               int* __restrict__ roff,
                                               int* __restrict__ coff){
  __shared__ int sh[256];
  int t = threadIdx.x;
  for (int arr = 0; arr < 2; ++arr){
    int v = (t < 196) ? bsum[arr * 196 + t] : 0;
    sh[t] = v; __syncthreads();
    for (int o = 1; o < 256; o <<= 1){
      int x = (t >= o) ? sh[t - o] : 0;
      __syncthreads();
      sh[t] += x;
      __syncthreads();
    }
    if (t < 196) bsum[arr * 196 + t] = sh[t] - v;   // exclusive
    __syncthreads();
  }
  if (t == 0){ roff[NN] = NE; coff[NN] = NE; }
}

__global__ __launch_bounds__(256) void k_scanC(const int* __restrict__ cnt,
                                               const int* __restrict__ bsum,
                                               int* __restrict__ roff,
                                               int* __restrict__ coff){
  __shared__ int sh[256];
  int b = blockIdx.x, t = threadIdx.x;
  int arr = b / 196, ib = b % 196;
  int i = ib * 256 + t;
  int v = (i < NN) ? cnt[arr * NN + i] : 0;
  sh[t] = v; __syncthreads();
  for (int o = 1; o < 256; o <<= 1){
    int x = (t >= o) ? sh[t - o] : 0;
    __syncthreads();
    sh[t] += x;
    __syncthreads();
  }
  int excl = sh[t] - v + bsum[b];
  if (i < NN){
    if (arr == 0) roff[i] = excl; else coff[i] = excl;
  }
}

__global__ void k_fill(const int* __restrict__ ei, const int* __restrict__ roff,
                       const int* __restrict__ coff, int* __restrict__ cur,
                       int* __restrict__ rdst, int* __restrict__ csrc){
  int e = blockIdx.x * blockDim.x + threadIdx.x;
  if (e < NE){
    int r = ei[e], c = ei[NE + e];
    int pr = roff[r] + atomicAdd(&cur[r], 1);
    rdst[pr] = c;
    int pc = coff[c] + atomicAdd(&cur[NN + c], 1);
    csrc[pc] = r;
  }
}

// K2: agg[n] = sum_{e: col=n} xd[row_e]  (CSR gather, no atomics)
__global__ __launch_bounds__(256) void k_agg2(const int* __restrict__ coff,
                                              const int* __restrict__ csrc,
                                              const float* __restrict__ xd,
                                              float* __restrict__ agg){
  int gid = blockIdx.x * blockDim.x + threadIdx.x;
  int lane = gid & 63, wid = gid >> 6;
  int nw = (gridDim.x * blockDim.x) >> 6;
  for (int n = wid; n < NN; n += nw){
    int st = coff[n], en = coff[n + 1];
    float a0 = 0.f, a1 = 0.f, a2 = 0.f, a3 = 0.f;
    int e = st;
    for (; e + 3 < en; e += 4){
      int s0 = csrc[e], s1 = csrc[e + 1], s2 = csrc[e + 2], s3 = csrc[e + 3];
      a0 += xd[(s0 << 6) + lane];
      a1 += xd[(s1 << 6) + lane];
      a2 += xd[(s2 << 6) + lane];
      a3 += xd[(s3 << 6) + lane];
    }
    for (; e < en; ++e) a0 += xd[(csrc[e] << 6) + lane];
    agg[(n << 6) + lane] = (a0 + a1) + (a2 + a3);
  }
}

// K3: x1 = relu(agg @ W1_rel^T + b1 + x_drop @ W1_root^T)
__global__ __launch_bounds__(128) void k_x1(const float* __restrict__ agg,
                                            const float* __restrict__ xd,
                                            const float* __restrict__ wts,
                                            float* __restrict__ x1){
  __shared__ float nb[4][2][INC];
  int t = threadIdx.x;
  float wr[64], wo[64];
#pragma unroll
  for (int j = 0; j < 64; ++j){
    wr[j] = wts[OFW_W1R + t * 64 + j];
    wo[j] = wts[OFW_W1O + t * 64 + j];
  }
  float bias = wts[OFW_B1 + t];
  for (int n0 = blockIdx.x * 4; n0 < NN; n0 += gridDim.x * 4){
#pragma unroll
    for (int u = 0; u < 4; ++u){
      int node = n0 + u;
      int m = (t >> 6) & 1;
      int k = t & 63;
      nb[u][m][k] = m ? xd[(node << 6) + k] : agg[(node << 6) + k];
    }
    __syncthreads();
#pragma unroll
    for (int a = 0; a < 4; ++a){
      float acc = bias;
#pragma unroll
      for (int j = 0; j < 64; ++j)
        acc += nb[a][0][j] * wr[j] + nb[a][1][j] * wo[j];
      x1[(n0 + a) * HC + t] = fmaxf(acc, 0.0f);
    }
    __syncthreads();
  }
}

// K4: s1 = LN(x1 @ pW1^T + pb1); s=softmax fp32, ls1=log_softmax to out,
//     den += deg[n]*||s_n||^2 (deg from CSR row offsets). One wave per node.
__global__ __launch_bounds__(256) void k_s1(const float* __restrict__ x1,
                                            const float* __restrict__ wts,
                                            const int* __restrict__ roff,
                                            float* __restrict__ s,
                                            void* __restrict__ outp,
                                            const float* __restrict__ flag,
                                            float* __restrict__ scal){
  __shared__ float pw[NC1 * 129];
  __shared__ float pb[NC1], gg[NC1], bb[NC1];
  __shared__ float wden[4];
  int t = threadIdx.x;
  for (int i = t; i < NC1 * HC; i += 256){
    int c = i >> 7, kk = i & 127;
    pw[c * 129 + kk] = wts[OFW_PW1 + i];
  }
  if (t < NC1){
    pb[t] = wts[OFW_PB1 + t];
    gg[t] = wts[OFW_G1 + t];
    bb[t] = wts[OFW_BE1 + t];
  }
  bool bf = flag[0] > 0.5f;
  int lane = t & 63, wv = t >> 6;
  float dacc = 0.0f;
  __syncthreads();
  for (int n = blockIdx.x * 4 + wv; n < NN; n += gridDim.x * 4){
    const float* xr = x1 + n * HC;
    float acc = pb[lane];
#pragma unroll
    for (int kk = 0; kk < HC; ++kk)
      acc += xr[kk] * pw[lane * 129 + kk];
    float mu  = wave_sum(acc) * (1.0f / 64.0f);
    float d   = acc - mu;
    float var = wave_sum(d * d) * (1.0f / 64.0f);
    float y   = d * rsqrtf(var + 1e-5f) * gg[lane] + bb[lane];
    float m   = wave_max(y);
    float ex  = expf(y - m);
    float se  = wave_sum(ex);
    float sv  = ex / se;
    s[n * NC1 + lane] = sv;
    store_out(outp, 4LL + (long long)n * NC1 + lane, (y - m) - logf(se), bf);
    float degn = (float)(roff[n + 1] - roff[n]);
    dacc += degn * sv * sv;
  }
  float wsum = wave_sum(dacc);
  if (lane == 0) wden[wv] = wsum;
  __syncthreads();
  if (t == 0) atomicAdd(&scal[0], wden[0] + wden[1] + wden[2] + wden[3]);
}

// K5: padj = sum_n s[n] (x) asrow[n],  asrow[n] = sum_{e:row=n} s[col_e]
#define PB 16
__global__ __launch_bounds__(256) void k_padj2(const int* __restrict__ roff,
                                               const int* __restrict__ rdst,
                                               const float* __restrict__ s,
                                               float* __restrict__ padj){
  __shared__ float rows[PB][2][64];
  int t = threadIdx.x;
  int lane = t & 63, w = t >> 6;
  int i4 = (t >> 4) << 2;
  int j4 = (t & 15) << 2;
  float acc[16];
#pragma unroll
  for (int m = 0; m < 16; ++m) acc[m] = 0.0f;
  const int nbatch = NN / PB;   // 3125
  for (int b = blockIdx.x; b < nbatch; b += gridDim.x){
    int base = b * PB;
#pragma unroll
    for (int q = 0; q < 4; ++q){
      int k = (w << 2) + q;
      int n = base + k;
      rows[k][0][lane] = s[(n << 6) + lane];
      int st = roff[n], en = roff[n + 1];
      float a0 = 0.f, a1 = 0.f, a2 = 0.f, a3 = 0.f;
      int e = st;
      for (; e + 3 < en; e += 4){
        int c0 = rdst[e], c1 = rdst[e + 1], c2 = rdst[e + 2], c3 = rdst[e + 3];
        a0 += s[(c0 << 6) + lane];
        a1 += s[(c1 << 6) + lane];
        a2 += s[(c2 << 6) + lane];
        a3 += s[(c3 << 6) + lane];
      }
      for (; e < en; ++e) a0 += s[(rdst[e] << 6) + lane];
      rows[k][1][lane] = (a0 + a1) + (a2 + a3);
    }
    __syncthreads();
#pragma unroll
    for (int k = 0; k < PB; ++k){
      float4 a  = *(const float4*)&rows[k][0][i4];
      float4 bb = *(const float4*)&rows[k][1][j4];
      acc[0]  += a.x * bb.x; acc[1]  += a.x * bb.y; acc[2]  += a.x * bb.z; acc[3]  += a.x * bb.w;
      acc[4]  += a.y * bb.x; acc[5]  += a.y * bb.y; acc[6]  += a.y * bb.z; acc[7]  += a.y * bb.w;
      acc[8]  += a.z * bb.x; acc[9]  += a.z * bb.y; acc[10] += a.z * bb.z; acc[11] += a.z * bb.w;
      acc[12] += a.w * bb.x; acc[13] += a.w * bb.y; acc[14] += a.w * bb.z; acc[15] += a.w * bb.w;
    }
    __syncthreads();
  }
#pragma unroll
  for (int m = 0; m < 16; ++m){
    int r = i4 + (m >> 2), c = j4 + (m & 3);
    atomicAdd(&padj[r * 64 + c], acc[m]);
  }
}

// K6: pooled_x = s^T x1, sTs = s^T s
__global__ __launch_bounds__(256) void k_pool(const float* __restrict__ s,
                                              const float* __restrict__ x1,
                                              float* __restrict__ px,
                                              float* __restrict__ sts){
  __shared__ float ssh[NC1], xsh[HC];
  int t = threadIdx.x;
  int c = t >> 2, q = t & 3;
  float apx[32], ast[16];
#pragma unroll
  for (int j = 0; j < 32; ++j) apx[j] = 0.0f;
#pragma unroll
  for (int j = 0; j < 16; ++j) ast[j] = 0.0f;
  for (int n = blockIdx.x; n < NN; n += gridDim.x){
    if (t < 64)       ssh[t]      = s[n * NC1 + t];
    else if (t < 192) xsh[t - 64] = x1[n * HC + (t - 64)];
    __syncthreads();
    float sv = ssh[c];
#pragma unroll
    for (int j = 0; j < 32; ++j) apx[j] += sv * xsh[q + 4 * j];
#pragma unroll
    for (int j = 0; j < 16; ++j) ast[j] += sv * ssh[q + 4 * j];
    __syncthreads();
  }
#pragma unroll
  for (int j = 0; j < 32; ++j) atomicAdd(&px[c * HC + q + 4 * j], apx[j]);
#pragma unroll
  for (int j = 0; j < 16; ++j) atomicAdd(&sts[c * NC1 + q + 4 * j], ast[j]);
}

// K7a: M, Mt, deg2, num1(trace), o1
__global__ __launch_bounds__(256) void k_m(const float* __restrict__ padj,
                                           const float* __restrict__ sts,
                                           float* __restrict__ Mg,
                                           float* __restrict__ Mtg,
                                           float* __restrict__ deg2,
                                           float* __restrict__ scal){
  __shared__ float red[256];
  __shared__ float psh[4096];
  __shared__ float dsi[64];
  int t = threadIdx.x;
  const float TH = 1.0f / 63.0f;
  for (int i = t; i < 4096; i += 256) psh[i] = padj[i];
  __syncthreads();
  float v = (t < 64) ? psh[t * 65] : 0.0f;
  float num1 = block_reduce_256(v, red, t);
  v = 0.0f;
  for (int i = t; i < 4096; i += 256){ float e = sts[i]; v += e * e; }
  float nrm1 = sqrtf(block_reduce_256(v, red, t));
  v = 0.0f;
  for (int i = t; i < 4096; i += 256){
    float e = sts[i] / (nrm1 + 1e-10f) - ((i % 65 == 0) ? 0.125f : 0.0f);
    v += e * e;
  }
  float o1 = sqrtf(block_reduce_256(v, red, t));
  if (t < 64){
    float rs = 0.0f;
    for (int j = 0; j < 64; ++j) rs += (j == t) ? 0.0f : psh[t * 64 + j];
    dsi[t] = 1.0f / (sqrtf(rs) + 1e-15f);
  }
  __syncthreads();
  for (int i = t; i < 4096; i += 256){
    int r = i >> 6, c = i & 63;
    float a = (r == c) ? 0.0f : psh[i];
    float m = (a * dsi[r] * dsi[c] > TH) ? 1.0f : 0.0f;
    Mg[i] = m;
    Mtg[c * 64 + r] = m;
  }
  __syncthreads();
  for (int i = t; i < 4096; i += 256){
    int r = i >> 6, c = i & 63;
    float a = (r == c) ? 0.0f : psh[i];
    psh[i] = (a * dsi[r] * dsi[c] > TH) ? 1.0f : 0.0f;
  }
  __syncthreads();
  if (t < 64){
    float d2 = 0.0f;
    for (int j = 0; j < 64; ++j) d2 += psh[t * 64 + j];
    deg2[t] = d2;
  }
  if (t == 0){ scal[1] = num1; scal[2] = o1; }
}

// K7b: per-cluster fused mp/x2/s2-logits/LN/softmax (64 blocks x 128 thr)
__global__ __launch_bounds__(128) void k_x2(const float* __restrict__ Mtg,
                                            const float* __restrict__ px,
                                            const float* __restrict__ wts,
                                            float* __restrict__ s2g,
                                            void* __restrict__ out,
                                            const float* __restrict__ flag){
  __shared__ float mt[64], pxc[128], mpsh[128], x2sh[128];
  __shared__ float part[16][9], lsh[16], stat[2];
  int c = blockIdx.x, t = threadIdx.x;
  if (t < 64) mt[t] = Mtg[c * 64 + t];
  pxc[t] = px[c * 128 + t];
  __syncthreads();
  float mp = 0.0f;
  for (int i = 0; i < 64; ++i) mp += mt[i] * px[i * 128 + t];
  mpsh[t] = mp;
  __syncthreads();
  float acc = wts[OFW_B2 + t];
  const float* wrr = wts + OFW_W2R + t * 128;
  const float* wor = wts + OFW_W2O + t * 128;
  for (int k = 0; k < 128; ++k) acc += mpsh[k] * wrr[k] + pxc[k] * wor[k];
  x2sh[t] = fmaxf(acc, 0.0f);
  __syncthreads();
  { int u = t >> 3, p = t & 7;
    const float* pw = wts + OFW_PW2 + u * 128 + p * 16;
    float pa = 0.0f;
    for (int k = 0; k < 16; ++k) pa += x2sh[p * 16 + k] * pw[k];
    part[u][p] = pa;
  }
  __syncthreads();
  if (t < 16){
    float l = wts[OFW_PB2 + t];
    for (int p = 0; p < 8; ++p) l += part[t][p];
    lsh[t] = l;
  }
  __syncthreads();
  if (t == 0){
    float mu = 0.0f;
    for (int u = 0; u < 16; ++u) mu += lsh[u];
    mu *= (1.0f / 16.0f);
    float var = 0.0f;
    for (int u = 0; u < 16; ++u){ float d = lsh[u] - mu; var += d * d; }
    var *= (1.0f / 16.0f);
    float rstd = rsqrtf(var + 1e-5f);
    float m = -3.4e38f;
    for (int u = 0; u < 16; ++u){
      lsh[u] = (lsh[u] - mu) * rstd * wts[OFW_G2 + u] + wts[OFW_BE2 + u];
      m = fmaxf(m, lsh[u]);
    }
    float se = 0.0f;
    for (int u = 0; u < 16; ++u) se += expf(lsh[u] - m);
    stat[0] = m; stat[1] = logf(se);
  }
  __syncthreads();
  if (t < 16){
    float ls = (lsh[t] - stat[0]) - stat[1];
    store_out(out, 4LL + (long long)NN * NC1 + c * 16 + t, ls, flag[0] > 0.5f);
    s2g[c * 16 + t] = expf(ls);
  }
}

// K7c: mc2 / o2 tail (1 block)
__global__ __launch_bounds__(256) void k_tail(const float* __restrict__ Mg,
                                              const float* __restrict__ s2g,
                                              const float* __restrict__ deg2,
                                              const float* __restrict__ scal,
                                              void* __restrict__ out,
                                              const float* __restrict__ flag){
  __shared__ float red[256];
  __shared__ float Msh[4096];
  __shared__ float s2sh[1024];
  __shared__ float d2sh[64];
  __shared__ float sts2[256];
  int t = threadIdx.x;
  for (int i = t; i < 4096; i += 256) Msh[i] = Mg[i];
  for (int i = t; i < 1024; i += 256) s2sh[i] = s2g[i];
  if (t < 64) d2sh[t] = deg2[t];
  __syncthreads();
  float vnum = 0.0f, vden = 0.0f;
  for (int m = 0; m < 4; ++m){
    int id = t + m * 256;
    int c = id >> 4, u = id & 15;
    float a = 0.0f;
    for (int j = 0; j < 64; ++j) a += Msh[c * 64 + j] * s2sh[j * 16 + u];
    float sv = s2sh[id];
    vnum += sv * a;
    vden += d2sh[c] * sv * sv;
  }
  float num2 = block_reduce_256(vnum, red, t);
  float den2 = block_reduce_256(vden, red, t) + 1e-10f;
  { int u = t >> 4, w = t & 15;
    float a = 0.0f;
    for (int c2 = 0; c2 < 64; ++c2) a += s2sh[c2 * 16 + u] * s2sh[c2 * 16 + w];
    sts2[t] = a;
  }
  __syncthreads();
  float v = sts2[t] * sts2[t];
  float nrm2 = sqrtf(block_reduce_256(v, red, t));
  { float e = sts2[t] / (nrm2 + 1e-10f) - (((t >> 4) == (t & 15)) ? 0.25f : 0.0f);
    v = e * e; }
  float o2 = sqrtf(block_reduce_256(v, red, t));
  if (t == 0){
    bool bf = flag[0] > 0.5f;
    float den = scal[0] + 1e-10f;
    store_out(out, 0, -scal[1] / den, bf);
    store_out(out, 1, scal[2], bf);
    store_out(out, 2, -num2 / den2, bf);
    store_out(out, 3, o2, bf);
  }
}

extern "C" void kernel_launch(void* const* d_in, const int* in_sizes, int n_in,
                              void* d_out, int out_size, void* d_ws, size_t ws_size,
                              hipStream_t stream){
  const void* x  = d_in[0];
  const int*  ei = (const int*)d_in[1];
  const void* dm = d_in[2];

  float* ws   = (float*)d_ws;
  float* flag = ws + OFF_FLAG;
  float* xd   = ws + OFF_XD;
  float* x1   = ws + OFF_X1;
  float* s    = ws + OFF_S;
  float* agg  = ws + OFF_AGG;
  float* px   = ws + OFF_PX;
  float* padj = ws + OFF_PADJ;
  float* sts  = ws + OFF_STS;
  float* scal = ws + OFF_SCAL;
  float* Mg   = ws + OFF_MG;
  float* Mtg  = ws + OFF_MTG;
  float* deg2 = ws + OFF_DEG2;
  float* s2g  = ws + OFF_S2G;
  int* roff = (int*)(ws + OFF_ROFF);
  int* coff = (int*)(ws + OFF_COFF);
  int* bsum = (int*)(ws + OFF_BSUM);
  int* csrc = (int*)(ws + OFF_CSRC);
  int* rdst = (int*)(ws + OFF_RDST);
  int* cnt  = (int*)(ws + OFF_CNT);
  int* cur  = (int*)(ws + OFF_CUR);

  hipMemsetAsync(ws + OFF_SCAL, 0, (size_t)ZERO_FLOATS * sizeof(float), stream);

  k_detect<<<1, 256, 0, stream>>>((const unsigned int*)dm, flag);
  k_cvt<<<(CVT_TOTAL + 255) / 256, 256, 0, stream>>>(
      d_in[3], d_in[5], d_in[4], d_in[6], d_in[7], d_in[8], d_in[9],
      d_in[10], d_in[11], d_in[12], d_in[13], d_in[14], d_in[15], d_in[16],
      flag, ws);
  k_xdrop<<<(NN * INC + 255) / 256, 256, 0, stream>>>(x, dm, flag, xd);
  k_hist<<<(NE + 255) / 256, 256, 0, stream>>>(ei, cnt);
  k_scanA<<<392, 256, 0, stream>>>(cnt, bsum);
  k_scanB<<<1, 256, 0, stream>>>(bsum, roff, coff);
  k_scanC<<<392, 256, 0, stream>>>(cnt, bsum, roff, coff);
  k_fill<<<(NE + 255) / 256, 256, 0, stream>>>(ei, roff, coff, cur, rdst, csrc);
  k_agg2<<<1024, 256, 0, stream>>>(coff, csrc, xd, agg);
  k_x1<<<2048, 128, 0, stream>>>(agg, xd, ws, x1);
  k_s1<<<2048, 256, 0, stream>>>(x1, ws, roff, s, d_out, flag, scal);
  k_padj2<<<1024, 256, 0, stream>>>(roff, rdst, s, padj);
  k_pool<<<512, 256, 0, stream>>>(s, x1, px, sts);
  k_m<<<1, 256, 0, stream>>>(padj, sts, Mg, Mtg, deg2, scal);
  k_x2<<<64, 128, 0, stream>>>(Mtg, px, ws, s2g, d_out, flag);
  k_tail<<<1, 256, 0, stream>>>(Mg, s2g, deg2, scal, d_out, flag);
}

// Round 5
// 823.041 us; speedup vs baseline: 1.1789x; 1.1789x over previous
//
#include <hip/hip_runtime.h>
#include <hip/hip_bf16.h>

#define NN 50000
#define NE 800000
#define INC 64
#define HC 128
#define NC1 64
#define NC2 16

// ---- workspace layout (float offsets) ----
#define OFF_FLAG 0
#define OFW_W1R 16
#define OFW_W1O 8208
#define OFW_B1  16400
#define OFW_PW1 16528
#define OFW_PB1 24720
#define OFW_G1  24784
#define OFW_BE1 24848
#define OFW_W2R 24912
#define OFW_B2  41296
#define OFW_W2O 41424
#define OFW_PW2 57808
#define OFW_PB2 59856
#define OFW_G2  59872
#define OFW_BE2 59888
#define CVT_TOTAL 59888

#define OFW_PW1T 59904
#define OFF_MG   68096
#define OFF_MTG  72192
#define OFF_DEG2 76288
#define OFF_S2G  76352
#define OFF_ROFF 77376
#define OFF_COFF 127380
#define OFF_BSUM 177384
#define OFF_XD   177792
#define OFF_X1   3377792
#define OFF_S    9777792
#define OFF_AGG  12977792
#define OFF_CSRC 16177792
#define OFF_RDST 16977792
// ---- zero region ----
#define OFF_SCAL 17777792
#define OFF_PX   17777808
#define OFF_PADJ 17786000
#define OFF_STS  17790096
#define OFF_CNT  17794192
#define OFF_CUR  17894192
#define OFF_END  17994192
#define ZERO_FLOATS (OFF_END - OFF_SCAL)

// overlays (dead buffers reused for reduction partials)
#define OFF_PXSTSP OFF_XD    // 256 * 12288 = 3145728 <= 3200000 (xd dead after k_x1)
#define OFF_PADJP  OFF_AGG   // 256 * 4096  = 1048576 <= 3200000 (agg dead after k_x1)
#define RED_P 256

__device__ inline float bflo(unsigned int u){ return __uint_as_float(u << 16); }
__device__ inline float bfhi(unsigned int u){ return __uint_as_float(u & 0xffff0000u); }

__device__ inline float wave_sum(float v){
#pragma unroll
  for (int o = 32; o > 0; o >>= 1) v += __shfl_xor(v, o, 64);
  return v;
}
__device__ inline float wave_max(float v){
#pragma unroll
  for (int o = 32; o > 0; o >>= 1) v = fmaxf(v, __shfl_xor(v, o, 64));
  return v;
}

__device__ inline void store_out(void* out, long long idx, float v, bool bf){
  if (bf) ((__hip_bfloat16*)out)[idx] = __float2bfloat16(v);
  else    ((float*)out)[idx] = v;
}

__device__ inline float block_reduce_256(float v, float* red, int t){
  red[t] = v; __syncthreads();
#pragma unroll
  for (int sh = 128; sh > 0; sh >>= 1){
    if (t < sh) red[t] += red[t + sh];
    __syncthreads();
  }
  float r = red[0];
  __syncthreads();
  return r;
}

// K0: detect input float dtype from drop_mask bit patterns.
__global__ void k_detect(const unsigned int* __restrict__ dmw, float* __restrict__ flag){
  __shared__ int cnt;
  if (threadIdx.x == 0) cnt = 0;
  __syncthreads();
  int c = 0;
  for (int i = threadIdx.x; i < 12288; i += 256){
    unsigned int w = dmw[i];
    if (w == 0x3F803F80u || w == 0x00003F80u) c++;
  }
  atomicAdd(&cnt, c);
  __syncthreads();
  if (threadIdx.x == 0) flag[0] = (cnt > 64) ? 1.0f : 0.0f;  // 1.0 => bf16 inputs
}

// K0b: convert all weight tensors to fp32 in ws (dst = 16 + i)
__global__ void k_cvt(const void* p0, const void* p1, const void* p2, const void* p3,
                      const void* p4, const void* p5, const void* p6, const void* p7,
                      const void* p8, const void* p9, const void* p10, const void* p11,
                      const void* p12, const void* p13,
                      const float* __restrict__ flag, float* __restrict__ ws){
  int i = blockIdx.x * blockDim.x + threadIdx.x;
  if (i >= CVT_TOTAL) return;
  const void* src; int off;
  if      (i < 8192 ){ src = p0;  off = i; }
  else if (i < 16384){ src = p1;  off = i - 8192; }
  else if (i < 16512){ src = p2;  off = i - 16384; }
  else if (i < 24704){ src = p3;  off = i - 16512; }
  else if (i < 24768){ src = p4;  off = i - 24704; }
  else if (i < 24832){ src = p5;  off = i - 24768; }
  else if (i < 24896){ src = p6;  off = i - 24832; }
  else if (i < 41280){ src = p7;  off = i - 24896; }
  else if (i < 41408){ src = p8;  off = i - 41280; }
  else if (i < 57792){ src = p9;  off = i - 41408; }
  else if (i < 59840){ src = p10; off = i - 57792; }
  else if (i < 59856){ src = p11; off = i - 59840; }
  else if (i < 59872){ src = p12; off = i - 59856; }
  else               { src = p13; off = i - 59872; }
  float v = (flag[0] > 0.5f) ? __bfloat162float(((const __hip_bfloat16*)src)[off])
                             : ((const float*)src)[off];
  ws[16 + i] = v;
}

// K0c: pw1T[k*64+c] = pw1[c*128+k]  (after k_cvt)
__global__ void k_trans(float* __restrict__ ws){
  int i = blockIdx.x * blockDim.x + threadIdx.x;
  if (i < 8192){
    int k = i >> 6, c = i & 63;
    ws[OFW_PW1T + i] = ws[OFW_PW1 + c * 128 + k];
  }
}

// K1: x_drop = drop_mask[:,None] * x  -> fp32 (4 elems/thread)
__global__ void k_xdrop(const void* __restrict__ xr, const void* __restrict__ dmr,
                        const float* __restrict__ flag, float* __restrict__ xd){
  int i4 = blockIdx.x * blockDim.x + threadIdx.x;
  if (i4 >= NN * 16) return;
  int n = i4 >> 4;
  float4 o;
  if (flag[0] > 0.5f){
    uint2 w = ((const uint2*)xr)[i4];
    float dv = __bfloat162float(((const __hip_bfloat16*)dmr)[n]);
    o.x = bflo(w.x) * dv; o.y = bfhi(w.x) * dv;
    o.z = bflo(w.y) * dv; o.w = bfhi(w.y) * dv;
  } else {
    float4 xv = ((const float4*)xr)[i4];
    float dv = ((const float*)dmr)[n];
    o.x = xv.x * dv; o.y = xv.y * dv; o.z = xv.z * dv; o.w = xv.w * dv;
  }
  ((float4*)xd)[i4] = o;
}

// ---- CSR build ----
__global__ void k_hist(const int* __restrict__ ei, int* __restrict__ cnt){
  int e = blockIdx.x * blockDim.x + threadIdx.x;
  if (e < NE){
    atomicAdd(&cnt[ei[e]], 1);            // row
    atomicAdd(&cnt[NN + ei[NE + e]], 1);  // col
  }
}

__global__ __launch_bounds__(256) void k_scanA(const int* __restrict__ cnt,
                                               int* __restrict__ bsum){
  __shared__ int red[256];
  int b = blockIdx.x;          // 0..391
  int arr = b / 196, ib = b % 196;
  int i = ib * 256 + threadIdx.x;
  int v = (i < NN) ? cnt[arr * NN + i] : 0;
  red[threadIdx.x] = v; __syncthreads();
#pragma unroll
  for (int sh = 128; sh > 0; sh >>= 1){
    if (threadIdx.x < sh) red[threadIdx.x] += red[threadIdx.x + sh];
    __syncthreads();
  }
  if (threadIdx.x == 0) bsum[b] = red[0];
}

__global__ __launch_bounds__(256) void k_scanB(int* __restrict__ bsum,
                                               int* __restrict__ roff,
                                               int* __restrict__ coff){
  __shared__ int sh[256];
  int t = threadIdx.x;
  for (int arr = 0; arr < 2; ++arr){
    int v = (t < 196) ? bsum[arr * 196 + t] : 0;
    sh[t] = v; __syncthreads();
    for (int o = 1; o < 256; o <<= 1){
      int x = (t >= o) ? sh[t - o] : 0;
      __syncthreads();
      sh[t] += x;
      __syncthreads();
    }
    if (t < 196) bsum[arr * 196 + t] = sh[t] - v;   // exclusive
    __syncthreads();
  }
  if (t == 0){ roff[NN] = NE; coff[NN] = NE; }
}

__global__ __launch_bounds__(256) void k_scanC(const int* __restrict__ cnt,
                                               const int* __restrict__ bsum,
                                               int* __restrict__ roff,
                                               int* __restrict__ coff){
  __shared__ int sh[256];
  int b = blockIdx.x, t = threadIdx.x;
  int arr = b / 196, ib = b % 196;
  int i = ib * 256 + t;
  int v = (i < NN) ? cnt[arr * NN + i] : 0;
  sh[t] = v; __syncthreads();
  for (int o = 1; o < 256; o <<= 1){
    int x = (t >= o) ? sh[t - o] : 0;
    __syncthreads();
    sh[t] += x;
    __syncthreads();
  }
  int excl = sh[t] - v + bsum[b];
  if (i < NN){
    if (arr == 0) roff[i] = excl; else coff[i] = excl;
  }
}

__global__ void k_fill(const int* __restrict__ ei, const int* __restrict__ roff,
                       const int* __restrict__ coff, int* __restrict__ cur,
                       int* __restrict__ rdst, int* __restrict__ csrc){
  int e = blockIdx.x * blockDim.x + threadIdx.x;
  if (e < NE){
    int r = ei[e], c = ei[NE + e];
    int pr = roff[r] + atomicAdd(&cur[r], 1);
    rdst[pr] = c;
    int pc = coff[c] + atomicAdd(&cur[NN + c], 1);
    csrc[pc] = r;
  }
}

// ---- lane-parallel CSR row-gather: sum_{e in [st,en)} table[idx[e]] (64-float rows)
// lane = (g, sub): g=lane>>4 picks edge slot, sub=lane&15 picks float4 column.
__device__ inline float4 gather_rowsum(const int* __restrict__ idxarr, int st, int en,
                                       const float* __restrict__ table, int lane,
                                       int g, int sub){
  float4 a0 = {0,0,0,0}, a1 = {0,0,0,0}, a2 = {0,0,0,0}, a3 = {0,0,0,0};
  for (int bb = st; bb < en; bb += 64){
    int rem = en - bb;
    int myi = (bb + lane < en) ? idxarr[bb + lane] : 0;
    int niter = ((rem < 64 ? rem : 64) + 3) >> 2;
    int i = 0;
    for (; i + 4 <= niter; i += 4){
      int s0 = __shfl(myi, g + ((i    ) << 2), 64);
      int s1 = __shfl(myi, g + ((i + 1) << 2), 64);
      int s2 = __shfl(myi, g + ((i + 2) << 2), 64);
      int s3 = __shfl(myi, g + ((i + 3) << 2), 64);
      // all slots < 16*4 <= min(rem,64) here only if full; guard each
      if ((g + (i << 2))       < rem){ float4 v = *(const float4*)(table + (s0 << 6) + (sub << 2)); a0.x += v.x; a0.y += v.y; a0.z += v.z; a0.w += v.w; }
      if ((g + ((i + 1) << 2)) < rem){ float4 v = *(const float4*)(table + (s1 << 6) + (sub << 2)); a1.x += v.x; a1.y += v.y; a1.z += v.z; a1.w += v.w; }
      if ((g + ((i + 2) << 2)) < rem){ float4 v = *(const float4*)(table + (s2 << 6) + (sub << 2)); a2.x += v.x; a2.y += v.y; a2.z += v.z; a2.w += v.w; }
      if ((g + ((i + 3) << 2)) < rem){ float4 v = *(const float4*)(table + (s3 << 6) + (sub << 2)); a3.x += v.x; a3.y += v.y; a3.z += v.z; a3.w += v.w; }
    }
    for (; i < niter; ++i){
      int slot = g + (i << 2);
      int s0 = __shfl(myi, slot, 64);
      if (slot < rem){ float4 v = *(const float4*)(table + (s0 << 6) + (sub << 2)); a0.x += v.x; a0.y += v.y; a0.z += v.z; a0.w += v.w; }
    }
  }
  float4 a;
  a.x = (a0.x + a1.x) + (a2.x + a3.x);
  a.y = (a0.y + a1.y) + (a2.y + a3.y);
  a.z = (a0.z + a1.z) + (a2.z + a3.z);
  a.w = (a0.w + a1.w) + (a2.w + a3.w);
  // reduce across the 4 groups
  a.x += __shfl_xor(a.x, 16, 64); a.x += __shfl_xor(a.x, 32, 64);
  a.y += __shfl_xor(a.y, 16, 64); a.y += __shfl_xor(a.y, 32, 64);
  a.z += __shfl_xor(a.z, 16, 64); a.z += __shfl_xor(a.z, 32, 64);
  a.w += __shfl_xor(a.w, 16, 64); a.w += __shfl_xor(a.w, 32, 64);
  return a;  // valid in all lanes; g==0 lanes hold the row slice for their sub
}

// K2: agg[n] = sum_{e: col=n} xd[csrc[e]]
__global__ __launch_bounds__(256) void k_agg2(const int* __restrict__ coff,
                                              const int* __restrict__ csrc,
                                              const float* __restrict__ xd,
                                              float* __restrict__ agg){
  int gid = blockIdx.x * 256 + threadIdx.x;
  int lane = gid & 63, wid = gid >> 6;
  int nw = (gridDim.x * 256) >> 6;
  int g = lane >> 4, sub = lane & 15;
  for (int n = wid; n < NN; n += nw){
    int st = coff[n], en = coff[n + 1];
    float4 a = gather_rowsum(csrc, st, en, xd, lane, g, sub);
    if (g == 0) *(float4*)(agg + (n << 6) + (sub << 2)) = a;
  }
}

// K3: x1 = relu(agg @ W1_rel^T + b1 + x_drop @ W1_root^T), 8-node batches
__global__ __launch_bounds__(128) void k_x1(const float* __restrict__ agg,
                                            const float* __restrict__ xd,
                                            const float* __restrict__ wts,
                                            float* __restrict__ x1){
  __shared__ float nb[8][2][64];
  int t = threadIdx.x;
  float wr[64], wo[64];
#pragma unroll
  for (int j = 0; j < 64; ++j){
    wr[j] = wts[OFW_W1R + t * 64 + j];
    wo[j] = wts[OFW_W1O + t * 64 + j];
  }
  float bias = wts[OFW_B1 + t];
  const int nbatch = NN / 8;   // 6250
  for (int b = blockIdx.x; b < nbatch; b += gridDim.x){
    int base = b * 8;
#pragma unroll
    for (int i = 0; i < 2; ++i){
      int f = t + (i << 7);        // float4 slot 0..255
      int u = f >> 5;              // node 0..7
      int j = f & 31;              // 0-15: agg, 16-31: xd
      const float* src = (j < 16) ? (agg + ((base + u) << 6) + (j << 2))
                                  : (xd  + ((base + u) << 6) + ((j - 16) << 2));
      *(float4*)&nb[u][j >> 4][(j & 15) << 2] = *(const float4*)src;
    }
    __syncthreads();
#pragma unroll
    for (int u = 0; u < 8; ++u){
      float acc_a = bias, acc_x = 0.0f;
#pragma unroll
      for (int j = 0; j < 16; ++j){
        float4 va = *(const float4*)&nb[u][0][j << 2];
        float4 vx = *(const float4*)&nb[u][1][j << 2];
        acc_a += va.x * wr[4*j] + va.y * wr[4*j+1] + va.z * wr[4*j+2] + va.w * wr[4*j+3];
        acc_x += vx.x * wo[4*j] + vx.y * wo[4*j+1] + vx.z * wo[4*j+2] + vx.w * wo[4*j+3];
      }
      x1[(base + u) * HC + t] = fmaxf(acc_a + acc_x, 0.0f);
    }
    __syncthreads();
  }
}

// K4: s1 = LN(x1 @ pW1^T + pb1); s=softmax fp32, ls1=log_softmax to out,
//     den += deg[n]*||s_n||^2. One wave per node. pW1 pre-transposed (k-major).
__global__ __launch_bounds__(256) void k_s1(const float* __restrict__ x1,
                                            const float* __restrict__ wts,
                                            const int* __restrict__ roff,
                                            float* __restrict__ s,
                                            void* __restrict__ outp,
                                            const float* __restrict__ flag,
                                            float* __restrict__ scal){
  __shared__ float pwT[HC * NC1];   // [k][c]
  __shared__ float pb[NC1], gg[NC1], bb[NC1];
  __shared__ float wden[4];
  int t = threadIdx.x;
  for (int i = t; i < HC * NC1; i += 256) pwT[i] = wts[OFW_PW1T + i];
  if (t < NC1){
    pb[t] = wts[OFW_PB1 + t];
    gg[t] = wts[OFW_G1 + t];
    bb[t] = wts[OFW_BE1 + t];
  }
  bool bf = flag[0] > 0.5f;
  int lane = t & 63, wv = t >> 6;
  float dacc = 0.0f;
  __syncthreads();
  for (int n = blockIdx.x * 4 + wv; n < NN; n += gridDim.x * 4){
    const float4* xr4 = (const float4*)(x1 + n * HC);
    float acc0 = pb[lane], acc1 = 0.0f;
#pragma unroll
    for (int kk = 0; kk < 32; ++kk){
      float4 xv = xr4[kk];
      acc0 += xv.x * pwT[(4*kk + 0) * 64 + lane] + xv.y * pwT[(4*kk + 1) * 64 + lane];
      acc1 += xv.z * pwT[(4*kk + 2) * 64 + lane] + xv.w * pwT[(4*kk + 3) * 64 + lane];
    }
    float acc = acc0 + acc1;
    float mu  = wave_sum(acc) * (1.0f / 64.0f);
    float d   = acc - mu;
    float var = wave_sum(d * d) * (1.0f / 64.0f);
    float y   = d * rsqrtf(var + 1e-5f) * gg[lane] + bb[lane];
    float m   = wave_max(y);
    float ex  = expf(y - m);
    float se  = wave_sum(ex);
    float sv  = ex / se;
    s[n * NC1 + lane] = sv;
    store_out(outp, 4LL + (long long)n * NC1 + lane, (y - m) - logf(se), bf);
    float degn = (float)(roff[n + 1] - roff[n]);
    dacc += degn * sv * sv;
  }
  float wsum = wave_sum(dacc);
  if (lane == 0) wden[wv] = wsum;
  __syncthreads();
  if (t == 0) atomicAdd(&scal[0], wden[0] + wden[1] + wden[2] + wden[3]);
}

// K5: padj partials: padj = sum_n s[n] (x) asrow[n], asrow[n]=sum_{e:row=n} s[rdst[e]]
__global__ __launch_bounds__(256) void k_padj2(const int* __restrict__ roff,
                                               const int* __restrict__ rdst,
                                               const float* __restrict__ s,
                                               float* __restrict__ padjp){
  __shared__ float rs[16 * 64];
  __shared__ float ra[16 * 64];
  int t = threadIdx.x, lane = t & 63, w = t >> 6;
  int g = lane >> 4, sub = lane & 15;
  int i4 = t >> 4;        // 0..15 row group
  int j4 = t & 15;        // 0..15 col group
  float4 acc0 = {0,0,0,0}, acc1 = {0,0,0,0}, acc2 = {0,0,0,0}, acc3 = {0,0,0,0};
  const int nbatch = NN / 16;   // 3125
  for (int b = blockIdx.x; b < nbatch; b += gridDim.x){
    int base = b * 16;
#pragma unroll
    for (int q = 0; q < 4; ++q){
      int k = w * 4 + q;
      int n = base + k;
      int st = roff[n], en = roff[n + 1];
      float4 a = gather_rowsum(rdst, st, en, s, lane, g, sub);
      if (g == 0){
        *(float4*)&ra[k * 64 + (sub << 2)] = a;
      } else if (g == 1){
        *(float4*)&rs[k * 64 + (sub << 2)] = *(const float4*)(s + (n << 6) + (sub << 2));
      }
    }
    __syncthreads();
#pragma unroll
    for (int k = 0; k < 16; ++k){
      float4 a  = *(const float4*)&rs[k * 64 + (i4 << 2)];
      float4 bv = *(const float4*)&ra[k * 64 + (j4 << 2)];
      acc0.x += a.x * bv.x; acc0.y += a.x * bv.y; acc0.z += a.x * bv.z; acc0.w += a.x * bv.w;
      acc1.x += a.y * bv.x; acc1.y += a.y * bv.y; acc1.z += a.y * bv.z; acc1.w += a.y * bv.w;
      acc2.x += a.z * bv.x; acc2.y += a.z * bv.y; acc2.z += a.z * bv.z; acc2.w += a.z * bv.w;
      acc3.x += a.w * bv.x; acc3.y += a.w * bv.y; acc3.z += a.w * bv.z; acc3.w += a.w * bv.w;
    }
    __syncthreads();
  }
  float* pp = padjp + blockIdx.x * 4096;
  *(float4*)&pp[(i4 * 4 + 0) * 64 + (j4 << 2)] = acc0;
  *(float4*)&pp[(i4 * 4 + 1) * 64 + (j4 << 2)] = acc1;
  *(float4*)&pp[(i4 * 4 + 2) * 64 + (j4 << 2)] = acc2;
  *(float4*)&pp[(i4 * 4 + 3) * 64 + (j4 << 2)] = acc3;
}

// K6: px/sts partials. 32-node batches, float4 staged, conflict-free interleaved cols.
__global__ __launch_bounds__(256) void k_pool(const float* __restrict__ s,
                                              const float* __restrict__ x1,
                                              float* __restrict__ part){
  __shared__ float ssh[32 * 64];    // 8 KB
  __shared__ float xsh[32 * 128];   // 16 KB
  int t = threadIdx.x;
  int c = t >> 2, q = t & 3;
  float4 apx[8], ast[4];
#pragma unroll
  for (int m = 0; m < 8; ++m) apx[m] = make_float4(0, 0, 0, 0);
#pragma unroll
  for (int m = 0; m < 4; ++m) ast[m] = make_float4(0, 0, 0, 0);
  const int nbatch = (NN + 31) / 32;   // 1563 (last partial: 16 nodes)
  for (int b = blockIdx.x; b < nbatch; b += gridDim.x){
    int base = b * 32;
    int kmax = NN - base; if (kmax > 32) kmax = 32;
    // stage s: 512 float4
#pragma unroll
    for (int i = 0; i < 2; ++i){
      int f = t + (i << 8);
      int k = f >> 4, col = f & 15;
      float4 v = (k < kmax) ? *(const float4*)(s + ((base + k) << 6) + (col << 2))
                            : make_float4(0, 0, 0, 0);
      *(float4*)&ssh[k * 64 + (col << 2)] = v;
    }
    // stage x1: 1024 float4
#pragma unroll
    for (int i = 0; i < 4; ++i){
      int f = t + (i << 8);
      int k = f >> 5, col = f & 31;
      float4 v = (k < kmax) ? *(const float4*)(x1 + (base + k) * HC + (col << 2))
                            : make_float4(0, 0, 0, 0);
      *(float4*)&xsh[k * 128 + (col << 2)] = v;
    }
    __syncthreads();
    for (int k = 0; k < kmax; ++k){
      float sv = ssh[k * 64 + c];
#pragma unroll
      for (int m = 0; m < 8; ++m){
        float4 xv = *(const float4*)&xsh[k * 128 + m * 16 + (q << 2)];
        apx[m].x += sv * xv.x; apx[m].y += sv * xv.y;
        apx[m].z += sv * xv.z; apx[m].w += sv * xv.w;
      }
#pragma unroll
      for (int m = 0; m < 4; ++m){
        float4 v2 = *(const float4*)&ssh[k * 64 + m * 16 + (q << 2)];
        ast[m].x += sv * v2.x; ast[m].y += sv * v2.y;
        ast[m].z += sv * v2.z; ast[m].w += sv * v2.w;
      }
    }
    __syncthreads();
  }
  float* pp = part + blockIdx.x * 12288;
#pragma unroll
  for (int m = 0; m < 8; ++m)
    *(float4*)&pp[c * 128 + m * 16 + (q << 2)] = apx[m];
#pragma unroll
  for (int m = 0; m < 4; ++m)
    *(float4*)&pp[8192 + c * 64 + m * 16 + (q << 2)] = ast[m];
}

// K6b: reduce partials -> px, sts, padj
__global__ __launch_bounds__(256) void k_red(const float* __restrict__ pxstsp,
                                             const float* __restrict__ padjp,
                                             float* __restrict__ px,
                                             float* __restrict__ sts,
                                             float* __restrict__ padj){
  int i = blockIdx.x * 256 + threadIdx.x;   // 0..16383
  float a0 = 0, a1 = 0, a2 = 0, a3 = 0;
  if (i < 12288){
    const float* base = pxstsp + i;
    for (int p = 0; p < RED_P; p += 4){
      a0 += base[(p    ) * 12288];
      a1 += base[(p + 1) * 12288];
      a2 += base[(p + 2) * 12288];
      a3 += base[(p + 3) * 12288];
    }
    float r = (a0 + a1) + (a2 + a3);
    if (i < 8192) px[i] = r; else sts[i - 8192] = r;
  } else {
    const float* base = padjp + (i - 12288);
    for (int p = 0; p < RED_P; p += 4){
      a0 += base[(p    ) * 4096];
      a1 += base[(p + 1) * 4096];
      a2 += base[(p + 2) * 4096];
      a3 += base[(p + 3) * 4096];
    }
    padj[i - 12288] = (a0 + a1) + (a2 + a3);
  }
}

// K7a: M, Mt, deg2, num1(trace), o1
__global__ __launch_bounds__(256) void k_m(const float* __restrict__ padj,
                                           const float* __restrict__ sts,
                                           float* __restrict__ Mg,
                                           float* __restrict__ Mtg,
                                           float* __restrict__ deg2,
                                           float* __restrict__ scal){
  __shared__ float red[256];
  __shared__ float psh[4096];
  __shared__ float dsi[64];
  int t = threadIdx.x;
  const float TH = 1.0f / 63.0f;
  for (int i = t; i < 4096; i += 256) psh[i] = padj[i];
  __syncthreads();
  float v = (t < 64) ? psh[t * 65] : 0.0f;
  float num1 = block_reduce_256(v, red, t);
  v = 0.0f;
  for (int i = t; i < 4096; i += 256){ float e = sts[i]; v += e * e; }
  float nrm1 = sqrtf(block_reduce_256(v, red, t));
  v = 0.0f;
  for (int i = t; i < 4096; i += 256){
    float e = sts[i] / (nrm1 + 1e-10f) - ((i % 65 == 0) ? 0.125f : 0.0f);
    v += e * e;
  }
  float o1 = sqrtf(block_reduce_256(v, red, t));
  if (t < 64){
    float rs = 0.0f;
    for (int j = 0; j < 64; ++j) rs += (j == t) ? 0.0f : psh[t * 64 + j];
    dsi[t] = 1.0f / (sqrtf(rs) + 1e-15f);
  }
  __syncthreads();
  for (int i = t; i < 4096; i += 256){
    int r = i >> 6, c = i & 63;
    float a = (r == c) ? 0.0f : psh[i];
    float m = (a * dsi[r] * dsi[c] > TH) ? 1.0f : 0.0f;
    Mg[i] = m;
    Mtg[c * 64 + r] = m;
  }
  __syncthreads();
  for (int i = t; i < 4096; i += 256){
    int r = i >> 6, c = i & 63;
    float a = (r == c) ? 0.0f : psh[i];
    psh[i] = (a * dsi[r] * dsi[c] > TH) ? 1.0f : 0.0f;
  }
  __syncthreads();
  if (t < 64){
    float d2 = 0.0f;
    for (int j = 0; j < 64; ++j) d2 += psh[t * 64 + j];
    deg2[t] = d2;
  }
  if (t == 0){ scal[1] = num1; scal[2] = o1; }
}

// K7b: per-cluster fused mp/x2/s2-logits/LN/softmax (64 blocks x 128 thr)
__global__ __launch_bounds__(128) void k_x2(const float* __restrict__ Mtg,
                                            const float* __restrict__ px,
                                            const float* __restrict__ wts,
                                            float* __restrict__ s2g,
                                            void* __restrict__ out,
                                            const float* __restrict__ flag){
  __shared__ float mt[64], pxc[128], mpsh[128], x2sh[128];
  __shared__ float part[16][9], lsh[16], stat[2];
  int c = blockIdx.x, t = threadIdx.x;
  if (t < 64) mt[t] = Mtg[c * 64 + t];
  pxc[t] = px[c * 128 + t];
  __syncthreads();
  float mp = 0.0f;
  for (int i = 0; i < 64; ++i) mp += mt[i] * px[i * 128 + t];
  mpsh[t] = mp;
  __syncthreads();
  float acc = wts[OFW_B2 + t];
  const float* wrr = wts + OFW_W2R + t * 128;
  const float* wor = wts + OFW_W2O + t * 128;
  for (int k = 0; k < 128; ++k) acc += mpsh[k] * wrr[k] + pxc[k] * wor[k];
  x2sh[t] = fmaxf(acc, 0.0f);
  __syncthreads();
  { int u = t >> 3, p = t & 7;
    const float* pw = wts + OFW_PW2 + u * 128 + p * 16;
    float pa = 0.0f;
    for (int k = 0; k < 16; ++k) pa += x2sh[p * 16 + k] * pw[k];
    part[u][p] = pa;
  }
  __syncthreads();
  if (t < 16){
    float l = wts[OFW_PB2 + t];
    for (int p = 0; p < 8; ++p) l += part[t][p];
    lsh[t] = l;
  }
  __syncthreads();
  if (t == 0){
    float mu = 0.0f;
    for (int u = 0; u < 16; ++u) mu += lsh[u];
    mu *= (1.0f / 16.0f);
    float var = 0.0f;
    for (int u = 0; u < 16; ++u){ float d = lsh[u] - mu; var += d * d; }
    var *= (1.0f / 16.0f);
    float rstd = rsqrtf(var + 1e-5f);
    float m = -3.4e38f;
    for (int u = 0; u < 16; ++u){
      lsh[u] = (lsh[u] - mu) * rstd * wts[OFW_G2 + u] + wts[OFW_BE2 + u];
      m = fmaxf(m, lsh[u]);
    }
    float se = 0.0f;
    for (int u = 0; u < 16; ++u) se += expf(lsh[u] - m);
    stat[0] = m; stat[1] = logf(se);
  }
  __syncthreads();
  if (t < 16){
    float ls = (lsh[t] - stat[0]) - stat[1];
    store_out(out, 4LL + (long long)NN * NC1 + c * 16 + t, ls, flag[0] > 0.5f);
    s2g[c * 16 + t] = expf(ls);
  }
}

// K7c: mc2 / o2 tail (1 block)
__global__ __launch_bounds__(256) void k_tail(const float* __restrict__ Mg,
                                              const float* __restrict__ s2g,
                                              const float* __restrict__ deg2,
                                              const float* __restrict__ scal,
                                              void* __restrict__ out,
                                              const float* __restrict__ flag){
  __shared__ float red[256];
  __shared__ float Msh[4096];
  __shared__ float s2sh[1024];
  __shared__ float d2sh[64];
  __shared__ float sts2[256];
  int t = threadIdx.x;
  for (int i = t; i < 4096; i += 256) Msh[i] = Mg[i];
  for (int i = t; i < 1024; i += 256) s2sh[i] = s2g[i];
  if (t < 64) d2sh[t] = deg2[t];
  __syncthreads();
  float vnum = 0.0f, vden = 0.0f;
  for (int m = 0; m < 4; ++m){
    int id = t + m * 256;
    int c = id >> 4, u = id & 15;
    float a = 0.0f;
    for (int j = 0; j < 64; ++j) a += Msh[c * 64 + j] * s2sh[j * 16 + u];
    float sv = s2sh[id];
    vnum += sv * a;
    vden += d2sh[c] * sv * sv;
  }
  float num2 = block_reduce_256(vnum, red, t);
  float den2 = block_reduce_256(vden, red, t) + 1e-10f;
  { int u = t >> 4, w = t & 15;
    float a = 0.0f;
    for (int c2 = 0; c2 < 64; ++c2) a += s2sh[c2 * 16 + u] * s2sh[c2 * 16 + w];
    sts2[t] = a;
  }
  __syncthreads();
  float v = sts2[t] * sts2[t];
  float nrm2 = sqrtf(block_reduce_256(v, red, t));
  { float e = sts2[t] / (nrm2 + 1e-10f) - (((t >> 4) == (t & 15)) ? 0.25f : 0.0f);
    v = e * e; }
  float o2 = sqrtf(block_reduce_256(v, red, t));
  if (t == 0){
    bool bf = flag[0] > 0.5f;
    float den = scal[0] + 1e-10f;
    store_out(out, 0, -scal[1] / den, bf);
    store_out(out, 1, scal[2], bf);
    store_out(out, 2, -num2 / den2, bf);
    store_out(out, 3, o2, bf);
  }
}

extern "C" void kernel_launch(void* const* d_in, const int* in_sizes, int n_in,
                              void* d_out, int out_size, void* d_ws, size_t ws_size,
                              hipStream_t stream){
  const void* x  = d_in[0];
  const int*  ei = (const int*)d_in[1];
  const void* dm = d_in[2];

  float* ws    = (float*)d_ws;
  float* flag  = ws + OFF_FLAG;
  float* xd    = ws + OFF_XD;
  float* x1    = ws + OFF_X1;
  float* s     = ws + OFF_S;
  float* agg   = ws + OFF_AGG;
  float* px    = ws + OFF_PX;
  float* padj  = ws + OFF_PADJ;
  float* sts   = ws + OFF_STS;
  float* scal  = ws + OFF_SCAL;
  float* Mg    = ws + OFF_MG;
  float* Mtg   = ws + OFF_MTG;
  float* deg2  = ws + OFF_DEG2;
  float* s2g   = ws + OFF_S2G;
  float* pxstsp= ws + OFF_PXSTSP;
  float* padjp = ws + OFF_PADJP;
  int* roff = (int*)(ws + OFF_ROFF);
  int* coff = (int*)(ws + OFF_COFF);
  int* bsum = (int*)(ws + OFF_BSUM);
  int* csrc = (int*)(ws + OFF_CSRC);
  int* rdst = (int*)(ws + OFF_RDST);
  int* cnt  = (int*)(ws + OFF_CNT);
  int* cur  = (int*)(ws + OFF_CUR);

  hipMemsetAsync(ws + OFF_SCAL, 0, (size_t)ZERO_FLOATS * sizeof(float), stream);

  k_detect<<<1, 256, 0, stream>>>((const unsigned int*)dm, flag);
  k_cvt<<<(CVT_TOTAL + 255) / 256, 256, 0, stream>>>(
      d_in[3], d_in[5], d_in[4], d_in[6], d_in[7], d_in[8], d_in[9],
      d_in[10], d_in[11], d_in[12], d_in[13], d_in[14], d_in[15], d_in[16],
      flag, ws);
  k_trans<<<32, 256, 0, stream>>>(ws);
  k_xdrop<<<(NN * 16 + 255) / 256, 256, 0, stream>>>(x, dm, flag, xd);
  k_hist<<<(NE + 255) / 256, 256, 0, stream>>>(ei, cnt);
  k_scanA<<<392, 256, 0, stream>>>(cnt, bsum);
  k_scanB<<<1, 256, 0, stream>>>(bsum, roff, coff);
  k_scanC<<<392, 256, 0, stream>>>(cnt, bsum, roff, coff);
  k_fill<<<(NE + 255) / 256, 256, 0, stream>>>(ei, roff, coff, cur, rdst, csrc);
  k_agg2<<<2048, 256, 0, stream>>>(coff, csrc, xd, agg);
  k_x1<<<1024, 128, 0, stream>>>(agg, xd, ws, x1);
  k_s1<<<2048, 256, 0, stream>>>(x1, ws, roff, s, d_out, flag, scal);
  k_padj2<<<RED_P, 256, 0, stream>>>(roff, rdst, s, padjp);
  k_pool<<<RED_P, 256, 0, stream>>>(s, x1, pxstsp);
  k_red<<<64, 256, 0, stream>>>(pxstsp, padjp, px, sts, padj);
  k_m<<<1, 256, 0, stream>>>(padj, sts, Mg, Mtg, deg2, scal);
  k_x2<<<64, 128, 0, stream>>>(Mtg, px, ws, s2g, d_out, flag);
  k_tail<<<1, 256, 0, stream>>>(Mg, s2g, deg2, scal, d_out, flag);
}

// Round 6
// 618.942 us; speedup vs baseline: 1.5677x; 1.3298x over previous
//
#include <hip/hip_runtime.h>
#include <hip/hip_bf16.h>

#define NN 50000
#define NE 800000
#define INC 64
#define HC 128
#define NC1 64
#define NC2 16

// ---- workspace layout (float offsets) ----
#define OFF_FLAG 0
#define OFW_W1R 16
#define OFW_W1O 8208
#define OFW_B1  16400
#define OFW_PW1 16528
#define OFW_PB1 24720
#define OFW_G1  24784
#define OFW_BE1 24848
#define OFW_W2R 24912
#define OFW_B2  41296
#define OFW_W2O 41424
#define OFW_PW2 57808
#define OFW_PB2 59856
#define OFW_G2  59872
#define OFW_BE2 59888
#define CVT_TOTAL 59888

#define OFW_PW1T 59904
#define OFF_MG   68096
#define OFF_MTG  72192
#define OFF_DEG2 76288
#define OFF_S2G  76352
#define OFF_ROFF 77376
#define OFF_COFF 127380
#define OFF_BSUM 177384
#define OFF_XD   177792
#define OFF_X1   3377792
#define OFF_S    9777792
#define OFF_AGG  12977792
#define OFF_CSRC 16177792
#define OFF_RDST 16977792
// ---- zero region ----
#define OFF_SCAL 17777792
#define OFF_PX   17777808
#define OFF_PADJ 17786000
#define OFF_STS  17790096
#define OFF_CNT  17794192
#define OFF_CUR  17894192
#define OFF_END  17994192
#define ZERO_FLOATS (OFF_END - OFF_SCAL)

// overlays (dead buffers reused)
#define OFF_PXSTSP OFF_XD    // 256 * 12288 = 3145728 <= 3200000 (xd dead after k_x1)
#define OFF_S1LOG  OFF_AGG   // 50000 * 64 = 3200000 (agg dead after k_x1)
#define OFF_PADJP  OFF_X1    // 1024 * 4096 = 4194304 <= 6400000 (x1 dead after k_pool)
#define P_POOL 256
#define P_PADJ 1024

__device__ inline float bflo(unsigned int u){ return __uint_as_float(u << 16); }
__device__ inline float bfhi(unsigned int u){ return __uint_as_float(u & 0xffff0000u); }

__device__ inline float wave_sum(float v){
#pragma unroll
  for (int o = 32; o > 0; o >>= 1) v += __shfl_xor(v, o, 64);
  return v;
}
__device__ inline float wave_max(float v){
#pragma unroll
  for (int o = 32; o > 0; o >>= 1) v = fmaxf(v, __shfl_xor(v, o, 64));
  return v;
}

__device__ inline void store_out(void* out, long long idx, float v, bool bf){
  if (bf) ((__hip_bfloat16*)out)[idx] = __float2bfloat16(v);
  else    ((float*)out)[idx] = v;
}

__device__ inline float block_reduce_256(float v, float* red, int t){
  red[t] = v; __syncthreads();
#pragma unroll
  for (int sh = 128; sh > 0; sh >>= 1){
    if (t < sh) red[t] += red[t + sh];
    __syncthreads();
  }
  float r = red[0];
  __syncthreads();
  return r;
}

// K0: detect input float dtype from drop_mask bit patterns.
__global__ void k_detect(const unsigned int* __restrict__ dmw, float* __restrict__ flag){
  __shared__ int cnt;
  if (threadIdx.x == 0) cnt = 0;
  __syncthreads();
  int c = 0;
  for (int i = threadIdx.x; i < 12288; i += 256){
    unsigned int w = dmw[i];
    if (w == 0x3F803F80u || w == 0x00003F80u) c++;
  }
  atomicAdd(&cnt, c);
  __syncthreads();
  if (threadIdx.x == 0) flag[0] = (cnt > 64) ? 1.0f : 0.0f;  // 1.0 => bf16 inputs
}

// K0b: convert all weight tensors to fp32 in ws (dst = 16 + i)
__global__ void k_cvt(const void* p0, const void* p1, const void* p2, const void* p3,
                      const void* p4, const void* p5, const void* p6, const void* p7,
                      const void* p8, const void* p9, const void* p10, const void* p11,
                      const void* p12, const void* p13,
                      const float* __restrict__ flag, float* __restrict__ ws){
  int i = blockIdx.x * blockDim.x + threadIdx.x;
  if (i >= CVT_TOTAL) return;
  const void* src; int off;
  if      (i < 8192 ){ src = p0;  off = i; }
  else if (i < 16384){ src = p1;  off = i - 8192; }
  else if (i < 16512){ src = p2;  off = i - 16384; }
  else if (i < 24704){ src = p3;  off = i - 16512; }
  else if (i < 24768){ src = p4;  off = i - 24704; }
  else if (i < 24832){ src = p5;  off = i - 24768; }
  else if (i < 24896){ src = p6;  off = i - 24832; }
  else if (i < 41280){ src = p7;  off = i - 24896; }
  else if (i < 41408){ src = p8;  off = i - 41280; }
  else if (i < 57792){ src = p9;  off = i - 41408; }
  else if (i < 59840){ src = p10; off = i - 57792; }
  else if (i < 59856){ src = p11; off = i - 59840; }
  else if (i < 59872){ src = p12; off = i - 59856; }
  else               { src = p13; off = i - 59872; }
  float v = (flag[0] > 0.5f) ? __bfloat162float(((const __hip_bfloat16*)src)[off])
                             : ((const float*)src)[off];
  ws[16 + i] = v;
}

// K0c: pw1T[k*64+c] = pw1[c*128+k]  (after k_cvt)
__global__ void k_trans(float* __restrict__ ws){
  int i = blockIdx.x * blockDim.x + threadIdx.x;
  if (i < 8192){
    int k = i >> 6, c = i & 63;
    ws[OFW_PW1T + i] = ws[OFW_PW1 + c * 128 + k];
  }
}

// K1: x_drop = drop_mask[:,None] * x  -> fp32 (4 elems/thread)
__global__ void k_xdrop(const void* __restrict__ xr, const void* __restrict__ dmr,
                        const float* __restrict__ flag, float* __restrict__ xd){
  int i4 = blockIdx.x * blockDim.x + threadIdx.x;
  if (i4 >= NN * 16) return;
  int n = i4 >> 4;
  float4 o;
  if (flag[0] > 0.5f){
    uint2 w = ((const uint2*)xr)[i4];
    float dv = __bfloat162float(((const __hip_bfloat16*)dmr)[n]);
    o.x = bflo(w.x) * dv; o.y = bfhi(w.x) * dv;
    o.z = bflo(w.y) * dv; o.w = bfhi(w.y) * dv;
  } else {
    float4 xv = ((const float4*)xr)[i4];
    float dv = ((const float*)dmr)[n];
    o.x = xv.x * dv; o.y = xv.y * dv; o.z = xv.z * dv; o.w = xv.w * dv;
  }
  ((float4*)xd)[i4] = o;
}

// ---- CSR build ----
__global__ void k_hist(const int* __restrict__ ei, int* __restrict__ cnt){
  int e = blockIdx.x * blockDim.x + threadIdx.x;
  if (e < NE){
    atomicAdd(&cnt[ei[e]], 1);            // row
    atomicAdd(&cnt[NN + ei[NE + e]], 1);  // col
  }
}

__global__ __launch_bounds__(256) void k_scanA(const int* __restrict__ cnt,
                                               int* __restrict__ bsum){
  __shared__ int red[256];
  int b = blockIdx.x;          // 0..391
  int arr = b / 196, ib = b % 196;
  int i = ib * 256 + threadIdx.x;
  int v = (i < NN) ? cnt[arr * NN + i] : 0;
  red[threadIdx.x] = v; __syncthreads();
#pragma unroll
  for (int sh = 128; sh > 0; sh >>= 1){
    if (threadIdx.x < sh) red[threadIdx.x] += red[threadIdx.x + sh];
    __syncthreads();
  }
  if (threadIdx.x == 0) bsum[b] = red[0];
}

__global__ __launch_bounds__(256) void k_scanB(int* __restrict__ bsum,
                                               int* __restrict__ roff,
                                               int* __restrict__ coff){
  __shared__ int sh[256];
  int t = threadIdx.x;
  for (int arr = 0; arr < 2; ++arr){
    int v = (t < 196) ? bsum[arr * 196 + t] : 0;
    sh[t] = v; __syncthreads();
    for (int o = 1; o < 256; o <<= 1){
      int x = (t >= o) ? sh[t - o] : 0;
      __syncthreads();
      sh[t] += x;
      __syncthreads();
    }
    if (t < 196) bsum[arr * 196 + t] = sh[t] - v;   // exclusive
    __syncthreads();
  }
  if (t == 0){ roff[NN] = NE; coff[NN] = NE; }
}

__global__ __launch_bounds__(256) void k_scanC(const int* __restrict__ cnt,
                                               const int* __restrict__ bsum,
                                               int* __restrict__ roff,
                                               int* __restrict__ coff){
  __shared__ int sh[256];
  int b = blockIdx.x, t = threadIdx.x;
  int arr = b / 196, ib = b % 196;
  int i = ib * 256 + t;
  int v = (i < NN) ? cnt[arr * NN + i] : 0;
  sh[t] = v; __syncthreads();
  for (int o = 1; o < 256; o <<= 1){
    int x = (t >= o) ? sh[t - o] : 0;
    __syncthreads();
    sh[t] += x;
    __syncthreads();
  }
  int excl = sh[t] - v + bsum[b];
  if (i < NN){
    if (arr == 0) roff[i] = excl; else coff[i] = excl;
  }
}

__global__ void k_fill(const int* __restrict__ ei, const int* __restrict__ roff,
                       const int* __restrict__ coff, int* __restrict__ cur,
                       int* __restrict__ rdst, int* __restrict__ csrc){
  int e = blockIdx.x * blockDim.x + threadIdx.x;
  if (e < NE){
    int r = ei[e], c = ei[NE + e];
    int pr = roff[r] + atomicAdd(&cur[r], 1);
    rdst[pr] = c;
    int pc = coff[c] + atomicAdd(&cur[NN + c], 1);
    csrc[pc] = r;
  }
}

// ---- lane-parallel CSR row-gather: sum_{e in [st,en)} table[idx[e]] (64-float rows)
__device__ inline float4 gather_rowsum(const int* __restrict__ idxarr, int st, int en,
                                       const float* __restrict__ table, int lane,
                                       int g, int sub){
  float4 a0 = {0,0,0,0}, a1 = {0,0,0,0}, a2 = {0,0,0,0}, a3 = {0,0,0,0};
  for (int bb = st; bb < en; bb += 64){
    int rem = en - bb;
    int myi = (bb + lane < en) ? idxarr[bb + lane] : 0;
    int niter = ((rem < 64 ? rem : 64) + 3) >> 2;
    int i = 0;
    for (; i + 4 <= niter; i += 4){
      int s0 = __shfl(myi, g + ((i    ) << 2), 64);
      int s1 = __shfl(myi, g + ((i + 1) << 2), 64);
      int s2 = __shfl(myi, g + ((i + 2) << 2), 64);
      int s3 = __shfl(myi, g + ((i + 3) << 2), 64);
      if ((g + (i << 2))       < rem){ float4 v = *(const float4*)(table + (s0 << 6) + (sub << 2)); a0.x += v.x; a0.y += v.y; a0.z += v.z; a0.w += v.w; }
      if ((g + ((i + 1) << 2)) < rem){ float4 v = *(const float4*)(table + (s1 << 6) + (sub << 2)); a1.x += v.x; a1.y += v.y; a1.z += v.z; a1.w += v.w; }
      if ((g + ((i + 2) << 2)) < rem){ float4 v = *(const float4*)(table + (s2 << 6) + (sub << 2)); a2.x += v.x; a2.y += v.y; a2.z += v.z; a2.w += v.w; }
      if ((g + ((i + 3) << 2)) < rem){ float4 v = *(const float4*)(table + (s3 << 6) + (sub << 2)); a3.x += v.x; a3.y += v.y; a3.z += v.z; a3.w += v.w; }
    }
    for (; i < niter; ++i){
      int slot = g + (i << 2);
      int s0 = __shfl(myi, slot, 64);
      if (slot < rem){ float4 v = *(const float4*)(table + (s0 << 6) + (sub << 2)); a0.x += v.x; a0.y += v.y; a0.z += v.z; a0.w += v.w; }
    }
  }
  float4 a;
  a.x = (a0.x + a1.x) + (a2.x + a3.x);
  a.y = (a0.y + a1.y) + (a2.y + a3.y);
  a.z = (a0.z + a1.z) + (a2.z + a3.z);
  a.w = (a0.w + a1.w) + (a2.w + a3.w);
  a.x += __shfl_xor(a.x, 16, 64); a.x += __shfl_xor(a.x, 32, 64);
  a.y += __shfl_xor(a.y, 16, 64); a.y += __shfl_xor(a.y, 32, 64);
  a.z += __shfl_xor(a.z, 16, 64); a.z += __shfl_xor(a.z, 32, 64);
  a.w += __shfl_xor(a.w, 16, 64); a.w += __shfl_xor(a.w, 32, 64);
  return a;
}

// K2: agg[n] = sum_{e: col=n} xd[csrc[e]]
__global__ __launch_bounds__(256) void k_agg2(const int* __restrict__ coff,
                                              const int* __restrict__ csrc,
                                              const float* __restrict__ xd,
                                              float* __restrict__ agg){
  int gid = blockIdx.x * 256 + threadIdx.x;
  int lane = gid & 63, wid = gid >> 6;
  int nw = (gridDim.x * 256) >> 6;
  int g = lane >> 4, sub = lane & 15;
  for (int n = wid; n < NN; n += nw){
    int st = coff[n], en = coff[n + 1];
    float4 a = gather_rowsum(csrc, st, en, xd, lane, g, sub);
    if (g == 0) *(float4*)(agg + (n << 6) + (sub << 2)) = a;
  }
}

// K3: x1 = relu(agg @ W1_rel^T + b1 + x_drop @ W1_root^T), 8-node batches
__global__ __launch_bounds__(128) void k_x1(const float* __restrict__ agg,
                                            const float* __restrict__ xd,
                                            const float* __restrict__ wts,
                                            float* __restrict__ x1){
  __shared__ float nb[8][2][64];
  int t = threadIdx.x;
  float wr[64], wo[64];
#pragma unroll
  for (int j = 0; j < 64; ++j){
    wr[j] = wts[OFW_W1R + t * 64 + j];
    wo[j] = wts[OFW_W1O + t * 64 + j];
  }
  float bias = wts[OFW_B1 + t];
  const int nbatch = NN / 8;   // 6250
  for (int b = blockIdx.x; b < nbatch; b += gridDim.x){
    int base = b * 8;
#pragma unroll
    for (int i = 0; i < 2; ++i){
      int f = t + (i << 7);
      int u = f >> 5;
      int j = f & 31;
      const float* src = (j < 16) ? (agg + ((base + u) << 6) + (j << 2))
                                  : (xd  + ((base + u) << 6) + ((j - 16) << 2));
      *(float4*)&nb[u][j >> 4][(j & 15) << 2] = *(const float4*)src;
    }
    __syncthreads();
#pragma unroll
    for (int u = 0; u < 8; ++u){
      float acc_a = bias, acc_x = 0.0f;
#pragma unroll
      for (int j = 0; j < 16; ++j){
        float4 va = *(const float4*)&nb[u][0][j << 2];
        float4 vx = *(const float4*)&nb[u][1][j << 2];
        acc_a += va.x * wr[4*j] + va.y * wr[4*j+1] + va.z * wr[4*j+2] + va.w * wr[4*j+3];
        acc_x += vx.x * wo[4*j] + vx.y * wo[4*j+1] + vx.z * wo[4*j+2] + vx.w * wo[4*j+3];
      }
      x1[(base + u) * HC + t] = fmaxf(acc_a + acc_x, 0.0f);
    }
    __syncthreads();
  }
}

// K4a: s1log = x1 @ pW1^T + pb1  (tile GEMM: 64 nodes x 64 cols per block)
__global__ __launch_bounds__(256) void k_s1mm(const float* __restrict__ x1,
                                              const float* __restrict__ wts,
                                              float* __restrict__ s1log){
  __shared__ float xs[64 * 129];     // node-major, pad 129 (conflict-free)
  __shared__ float pwsh[HC * 64];    // [k][c]
  int t = threadIdx.x;
  int base = blockIdx.x * 64;
  for (int i = t; i < HC * 64; i += 256) pwsh[i] = wts[OFW_PW1T + i];
  for (int f = t; f < 64 * 32; f += 256){
    int r = f >> 5, kq = f & 31;
    float4 v = (base + r < NN) ? *(const float4*)(x1 + (base + r) * HC + (kq << 2))
                               : make_float4(0, 0, 0, 0);
    xs[r * 129 + 4*kq]     = v.x;
    xs[r * 129 + 4*kq + 1] = v.y;
    xs[r * 129 + 4*kq + 2] = v.z;
    xs[r * 129 + 4*kq + 3] = v.w;
  }
  __syncthreads();
  int ni = t >> 4, cj = t & 15;
  float4 c0 = {0,0,0,0}, c1 = {0,0,0,0}, c2 = {0,0,0,0}, c3 = {0,0,0,0};
#pragma unroll 4
  for (int k = 0; k < HC; ++k){
    float4 b = *(const float4*)&pwsh[k * 64 + (cj << 2)];
    float a0 = xs[(ni * 4 + 0) * 129 + k];
    float a1 = xs[(ni * 4 + 1) * 129 + k];
    float a2 = xs[(ni * 4 + 2) * 129 + k];
    float a3 = xs[(ni * 4 + 3) * 129 + k];
    c0.x += a0 * b.x; c0.y += a0 * b.y; c0.z += a0 * b.z; c0.w += a0 * b.w;
    c1.x += a1 * b.x; c1.y += a1 * b.y; c1.z += a1 * b.z; c1.w += a1 * b.w;
    c2.x += a2 * b.x; c2.y += a2 * b.y; c2.z += a2 * b.z; c2.w += a2 * b.w;
    c3.x += a3 * b.x; c3.y += a3 * b.y; c3.z += a3 * b.z; c3.w += a3 * b.w;
  }
  float4 pb = *(const float4*)&wts[OFW_PB1 + (cj << 2)];
  c0.x += pb.x; c0.y += pb.y; c0.z += pb.z; c0.w += pb.w;
  c1.x += pb.x; c1.y += pb.y; c1.z += pb.z; c1.w += pb.w;
  c2.x += pb.x; c2.y += pb.y; c2.z += pb.z; c2.w += pb.w;
  c3.x += pb.x; c3.y += pb.y; c3.z += pb.z; c3.w += pb.w;
  int r0 = base + ni * 4;
  if (r0 + 0 < NN) *(float4*)(s1log + (r0 + 0) * 64 + (cj << 2)) = c0;
  if (r0 + 1 < NN) *(float4*)(s1log + (r0 + 1) * 64 + (cj << 2)) = c1;
  if (r0 + 2 < NN) *(float4*)(s1log + (r0 + 2) * 64 + (cj << 2)) = c2;
  if (r0 + 3 < NN) *(float4*)(s1log + (r0 + 3) * 64 + (cj << 2)) = c3;
}

// K4b: LN + softmax/log_softmax over s1log rows; s fp32, ls1 to out, den accum.
__global__ __launch_bounds__(256) void k_s1ln(const float* __restrict__ s1log,
                                              const float* __restrict__ wts,
                                              const int* __restrict__ roff,
                                              float* __restrict__ s,
                                              void* __restrict__ outp,
                                              const float* __restrict__ flag,
                                              float* __restrict__ scal){
  __shared__ float gsh[64], bsh[64];
  __shared__ float wden[4];
  int t = threadIdx.x;
  if (t < 64){ gsh[t] = wts[OFW_G1 + t]; bsh[t] = wts[OFW_BE1 + t]; }
  bool bf = flag[0] > 0.5f;
  int lane = t & 63, wv = t >> 6;
  float dacc = 0.0f;
  __syncthreads();
  for (int n = blockIdx.x * 4 + wv; n < NN; n += gridDim.x * 4){
    float z = s1log[n * 64 + lane];
    float mu  = wave_sum(z) * (1.0f / 64.0f);
    float d   = z - mu;
    float var = wave_sum(d * d) * (1.0f / 64.0f);
    float y   = d * rsqrtf(var + 1e-5f) * gsh[lane] + bsh[lane];
    float m   = wave_max(y);
    float ex  = expf(y - m);
    float se  = wave_sum(ex);
    float sv  = ex / se;
    s[n * 64 + lane] = sv;
    store_out(outp, 4LL + (long long)n * 64 + lane, (y - m) - logf(se), bf);
    float degn = (float)(roff[n + 1] - roff[n]);
    dacc += degn * sv * sv;
  }
  float wsum = wave_sum(dacc);
  if (lane == 0) wden[wv] = wsum;
  __syncthreads();
  if (t == 0) atomicAdd(&scal[0], wden[0] + wden[1] + wden[2] + wden[3]);
}

// K5: padj partials: padj = sum_n s[n] (x) asrow[n], asrow[n]=sum_{e:row=n} s[rdst[e]]
__global__ __launch_bounds__(256) void k_padj2(const int* __restrict__ roff,
                                               const int* __restrict__ rdst,
                                               const float* __restrict__ s,
                                               float* __restrict__ padjp){
  __shared__ float rs[16 * 64];
  __shared__ float ra[16 * 64];
  int t = threadIdx.x, lane = t & 63, w = t >> 6;
  int g = lane >> 4, sub = lane & 15;
  int i4 = t >> 4;
  int j4 = t & 15;
  float4 acc0 = {0,0,0,0}, acc1 = {0,0,0,0}, acc2 = {0,0,0,0}, acc3 = {0,0,0,0};
  const int nbatch = NN / 16;   // 3125
  for (int b = blockIdx.x; b < nbatch; b += gridDim.x){
    int base = b * 16;
#pragma unroll
    for (int q = 0; q < 4; ++q){
      int k = w * 4 + q;
      int n = base + k;
      int st = roff[n], en = roff[n + 1];
      float4 a = gather_rowsum(rdst, st, en, s, lane, g, sub);
      if (g == 0){
        *(float4*)&ra[k * 64 + (sub << 2)] = a;
      } else if (g == 1){
        *(float4*)&rs[k * 64 + (sub << 2)] = *(const float4*)(s + (n << 6) + (sub << 2));
      }
    }
    __syncthreads();
#pragma unroll
    for (int k = 0; k < 16; ++k){
      float4 a  = *(const float4*)&rs[k * 64 + (i4 << 2)];
      float4 bv = *(const float4*)&ra[k * 64 + (j4 << 2)];
      acc0.x += a.x * bv.x; acc0.y += a.x * bv.y; acc0.z += a.x * bv.z; acc0.w += a.x * bv.w;
      acc1.x += a.y * bv.x; acc1.y += a.y * bv.y; acc1.z += a.y * bv.z; acc1.w += a.y * bv.w;
      acc2.x += a.z * bv.x; acc2.y += a.z * bv.y; acc2.z += a.z * bv.z; acc2.w += a.z * bv.w;
      acc3.x += a.w * bv.x; acc3.y += a.w * bv.y; acc3.z += a.w * bv.z; acc3.w += a.w * bv.w;
    }
    __syncthreads();
  }
  float* pp = padjp + blockIdx.x * 4096;
  *(float4*)&pp[(i4 * 4 + 0) * 64 + (j4 << 2)] = acc0;
  *(float4*)&pp[(i4 * 4 + 1) * 64 + (j4 << 2)] = acc1;
  *(float4*)&pp[(i4 * 4 + 2) * 64 + (j4 << 2)] = acc2;
  *(float4*)&pp[(i4 * 4 + 3) * 64 + (j4 << 2)] = acc3;
}

// K6: px/sts partials. 32-node batches, float4 staged, conflict-free interleaved cols.
__global__ __launch_bounds__(256) void k_pool(const float* __restrict__ s,
                                              const float* __restrict__ x1,
                                              float* __restrict__ part){
  __shared__ float ssh[32 * 64];
  __shared__ float xsh[32 * 128];
  int t = threadIdx.x;
  int c = t >> 2, q = t & 3;
  float4 apx[8], ast[4];
#pragma unroll
  for (int m = 0; m < 8; ++m) apx[m] = make_float4(0, 0, 0, 0);
#pragma unroll
  for (int m = 0; m < 4; ++m) ast[m] = make_float4(0, 0, 0, 0);
  const int nbatch = (NN + 31) / 32;
  for (int b = blockIdx.x; b < nbatch; b += gridDim.x){
    int base = b * 32;
    int kmax = NN - base; if (kmax > 32) kmax = 32;
#pragma unroll
    for (int i = 0; i < 2; ++i){
      int f = t + (i << 8);
      int k = f >> 4, col = f & 15;
      float4 v = (k < kmax) ? *(const float4*)(s + ((base + k) << 6) + (col << 2))
                            : make_float4(0, 0, 0, 0);
      *(float4*)&ssh[k * 64 + (col << 2)] = v;
    }
#pragma unroll
    for (int i = 0; i < 4; ++i){
      int f = t + (i << 8);
      int k = f >> 5, col = f & 31;
      float4 v = (k < kmax) ? *(const float4*)(x1 + (base + k) * HC + (col << 2))
                            : make_float4(0, 0, 0, 0);
      *(float4*)&xsh[k * 128 + (col << 2)] = v;
    }
    __syncthreads();
    for (int k = 0; k < kmax; ++k){
      float sv = ssh[k * 64 + c];
#pragma unroll
      for (int m = 0; m < 8; ++m){
        float4 xv = *(const float4*)&xsh[k * 128 + m * 16 + (q << 2)];
        apx[m].x += sv * xv.x; apx[m].y += sv * xv.y;
        apx[m].z += sv * xv.z; apx[m].w += sv * xv.w;
      }
#pragma unroll
      for (int m = 0; m < 4; ++m){
        float4 v2 = *(const float4*)&ssh[k * 64 + m * 16 + (q << 2)];
        ast[m].x += sv * v2.x; ast[m].y += sv * v2.y;
        ast[m].z += sv * v2.z; ast[m].w += sv * v2.w;
      }
    }
    __syncthreads();
  }
  float* pp = part + blockIdx.x * 12288;
#pragma unroll
  for (int m = 0; m < 8; ++m)
    *(float4*)&pp[c * 128 + m * 16 + (q << 2)] = apx[m];
#pragma unroll
  for (int m = 0; m < 4; ++m)
    *(float4*)&pp[8192 + c * 64 + m * 16 + (q << 2)] = ast[m];
}

// K6b: reduce partials -> px, sts (192 blocks) and padj (64 blocks). grid=256.
__global__ __launch_bounds__(256) void k_red(const float* __restrict__ pxstsp,
                                             const float* __restrict__ padjp,
                                             float* __restrict__ px,
                                             float* __restrict__ sts,
                                             float* __restrict__ padj){
  __shared__ float sh[256];
  int b = blockIdx.x, t = threadIdx.x;
  int ci = t & 63, pc = t >> 6;
  if (b < 192){
    int cell = b * 64 + ci;
    float a0 = 0, a1 = 0, a2 = 0, a3 = 0;
    const float* basep = pxstsp + cell;
    int p0 = pc * (P_POOL / 4);
    for (int p = 0; p < P_POOL / 4; p += 4){
      a0 += basep[(p0 + p    ) * 12288];
      a1 += basep[(p0 + p + 1) * 12288];
      a2 += basep[(p0 + p + 2) * 12288];
      a3 += basep[(p0 + p + 3) * 12288];
    }
    sh[t] = (a0 + a1) + (a2 + a3);
    __syncthreads();
    if (t < 64){
      float r = sh[t] + sh[t + 64] + sh[t + 128] + sh[t + 192];
      int cell2 = b * 64 + t;
      if (cell2 < 8192) px[cell2] = r; else sts[cell2 - 8192] = r;
    }
  } else {
    int cell = (b - 192) * 64 + ci;
    float a0 = 0, a1 = 0, a2 = 0, a3 = 0;
    const float* basep = padjp + cell;
    int p0 = pc * (P_PADJ / 4);
    for (int p = 0; p < P_PADJ / 4; p += 4){
      a0 += basep[(p0 + p    ) * 4096];
      a1 += basep[(p0 + p + 1) * 4096];
      a2 += basep[(p0 + p + 2) * 4096];
      a3 += basep[(p0 + p + 3) * 4096];
    }
    sh[t] = (a0 + a1) + (a2 + a3);
    __syncthreads();
    if (t < 64) padj[(b - 192) * 64 + t] = sh[t] + sh[t + 64] + sh[t + 128] + sh[t + 192];
  }
}

// K7a: M, Mt, deg2, num1(trace), o1
__global__ __launch_bounds__(256) void k_m(const float* __restrict__ padj,
                                           const float* __restrict__ sts,
                                           float* __restrict__ Mg,
                                           float* __restrict__ Mtg,
                                           float* __restrict__ deg2,
                                           float* __restrict__ scal){
  __shared__ float red[256];
  __shared__ float psh[4096];
  __shared__ float dsi[64];
  int t = threadIdx.x;
  const float TH = 1.0f / 63.0f;
  for (int i = t; i < 4096; i += 256) psh[i] = padj[i];
  __syncthreads();
  float v = (t < 64) ? psh[t * 65] : 0.0f;
  float num1 = block_reduce_256(v, red, t);
  v = 0.0f;
  for (int i = t; i < 4096; i += 256){ float e = sts[i]; v += e * e; }
  float nrm1 = sqrtf(block_reduce_256(v, red, t));
  v = 0.0f;
  for (int i = t; i < 4096; i += 256){
    float e = sts[i] / (nrm1 + 1e-10f) - ((i % 65 == 0) ? 0.125f : 0.0f);
    v += e * e;
  }
  float o1 = sqrtf(block_reduce_256(v, red, t));
  if (t < 64){
    float rs = 0.0f;
    for (int j = 0; j < 64; ++j) rs += (j == t) ? 0.0f : psh[t * 64 + j];
    dsi[t] = 1.0f / (sqrtf(rs) + 1e-15f);
  }
  __syncthreads();
  for (int i = t; i < 4096; i += 256){
    int r = i >> 6, c = i & 63;
    float a = (r == c) ? 0.0f : psh[i];
    float m = (a * dsi[r] * dsi[c] > TH) ? 1.0f : 0.0f;
    Mg[i] = m;
    Mtg[c * 64 + r] = m;
  }
  __syncthreads();
  for (int i = t; i < 4096; i += 256){
    int r = i >> 6, c = i & 63;
    float a = (r == c) ? 0.0f : psh[i];
    psh[i] = (a * dsi[r] * dsi[c] > TH) ? 1.0f : 0.0f;
  }
  __syncthreads();
  if (t < 64){
    float d2 = 0.0f;
    for (int j = 0; j < 64; ++j) d2 += psh[t * 64 + j];
    deg2[t] = d2;
  }
  if (t == 0){ scal[1] = num1; scal[2] = o1; }
}

// K7b: per-cluster fused mp/x2/s2-logits/LN/softmax (64 blocks x 128 thr)
__global__ __launch_bounds__(128) void k_x2(const float* __restrict__ Mtg,
                                            const float* __restrict__ px,
                                            const float* __restrict__ wts,
                                            float* __restrict__ s2g,
                                            void* __restrict__ out,
                                            const float* __restrict__ flag){
  __shared__ float mt[64], pxc[128], mpsh[128], x2sh[128];
  __shared__ float part[16][9], lsh[16], stat[2];
  int c = blockIdx.x, t = threadIdx.x;
  if (t < 64) mt[t] = Mtg[c * 64 + t];
  pxc[t] = px[c * 128 + t];
  __syncthreads();
  float mp = 0.0f;
  for (int i = 0; i < 64; ++i) mp += mt[i] * px[i * 128 + t];
  mpsh[t] = mp;
  __syncthreads();
  float acc = wts[OFW_B2 + t];
  const float* wrr = wts + OFW_W2R + t * 128;
  const float* wor = wts + OFW_W2O + t * 128;
  for (int k = 0; k < 128; ++k) acc += mpsh[k] * wrr[k] + pxc[k] * wor[k];
  x2sh[t] = fmaxf(acc, 0.0f);
  __syncthreads();
  { int u = t >> 3, p = t & 7;
    const float* pw = wts + OFW_PW2 + u * 128 + p * 16;
    float pa = 0.0f;
    for (int k = 0; k < 16; ++k) pa += x2sh[p * 16 + k] * pw[k];
    part[u][p] = pa;
  }
  __syncthreads();
  if (t < 16){
    float l = wts[OFW_PB2 + t];
    for (int p = 0; p < 8; ++p) l += part[t][p];
    lsh[t] = l;
  }
  __syncthreads();
  if (t == 0){
    float mu = 0.0f;
    for (int u = 0; u < 16; ++u) mu += lsh[u];
    mu *= (1.0f / 16.0f);
    float var = 0.0f;
    for (int u = 0; u < 16; ++u){ float d = lsh[u] - mu; var += d * d; }
    var *= (1.0f / 16.0f);
    float rstd = rsqrtf(var + 1e-5f);
    float m = -3.4e38f;
    for (int u = 0; u < 16; ++u){
      lsh[u] = (lsh[u] - mu) * rstd * wts[OFW_G2 + u] + wts[OFW_BE2 + u];
      m = fmaxf(m, lsh[u]);
    }
    float se = 0.0f;
    for (int u = 0; u < 16; ++u) se += expf(lsh[u] - m);
    stat[0] = m; stat[1] = logf(se);
  }
  __syncthreads();
  if (t < 16){
    float ls = (lsh[t] - stat[0]) - stat[1];
    store_out(out, 4LL + (long long)NN * NC1 + c * 16 + t, ls, flag[0] > 0.5f);
    s2g[c * 16 + t] = expf(ls);
  }
}

// K7c: mc2 / o2 tail (1 block)
__global__ __launch_bounds__(256) void k_tail(const float* __restrict__ Mg,
                                              const float* __restrict__ s2g,
                                              const float* __restrict__ deg2,
                                              const float* __restrict__ scal,
                                              void* __restrict__ out,
                                              const float* __restrict__ flag){
  __shared__ float red[256];
  __shared__ float Msh[4096];
  __shared__ float s2sh[1024];
  __shared__ float d2sh[64];
  __shared__ float sts2[256];
  int t = threadIdx.x;
  for (int i = t; i < 4096; i += 256) Msh[i] = Mg[i];
  for (int i = t; i < 1024; i += 256) s2sh[i] = s2g[i];
  if (t < 64) d2sh[t] = deg2[t];
  __syncthreads();
  float vnum = 0.0f, vden = 0.0f;
  for (int m = 0; m < 4; ++m){
    int id = t + m * 256;
    int c = id >> 4, u = id & 15;
    float a = 0.0f;
    for (int j = 0; j < 64; ++j) a += Msh[c * 64 + j] * s2sh[j * 16 + u];
    float sv = s2sh[id];
    vnum += sv * a;
    vden += d2sh[c] * sv * sv;
  }
  float num2 = block_reduce_256(vnum, red, t);
  float den2 = block_reduce_256(vden, red, t) + 1e-10f;
  { int u = t >> 4, w = t & 15;
    float a = 0.0f;
    for (int c2 = 0; c2 < 64; ++c2) a += s2sh[c2 * 16 + u] * s2sh[c2 * 16 + w];
    sts2[t] = a;
  }
  __syncthreads();
  float v = sts2[t] * sts2[t];
  float nrm2 = sqrtf(block_reduce_256(v, red, t));
  { float e = sts2[t] / (nrm2 + 1e-10f) - (((t >> 4) == (t & 15)) ? 0.25f : 0.0f);
    v = e * e; }
  float o2 = sqrtf(block_reduce_256(v, red, t));
  if (t == 0){
    bool bf = flag[0] > 0.5f;
    float den = scal[0] + 1e-10f;
    store_out(out, 0, -scal[1] / den, bf);
    store_out(out, 1, scal[2], bf);
    store_out(out, 2, -num2 / den2, bf);
    store_out(out, 3, o2, bf);
  }
}

extern "C" void kernel_launch(void* const* d_in, const int* in_sizes, int n_in,
                              void* d_out, int out_size, void* d_ws, size_t ws_size,
                              hipStream_t stream){
  const void* x  = d_in[0];
  const int*  ei = (const int*)d_in[1];
  const void* dm = d_in[2];

  float* ws    = (float*)d_ws;
  float* flag  = ws + OFF_FLAG;
  float* xd    = ws + OFF_XD;
  float* x1    = ws + OFF_X1;
  float* s     = ws + OFF_S;
  float* agg   = ws + OFF_AGG;
  float* px    = ws + OFF_PX;
  float* padj  = ws + OFF_PADJ;
  float* sts   = ws + OFF_STS;
  float* scal  = ws + OFF_SCAL;
  float* Mg    = ws + OFF_MG;
  float* Mtg   = ws + OFF_MTG;
  float* deg2  = ws + OFF_DEG2;
  float* s2g   = ws + OFF_S2G;
  float* pxstsp= ws + OFF_PXSTSP;
  float* padjp = ws + OFF_PADJP;
  float* s1log = ws + OFF_S1LOG;
  int* roff = (int*)(ws + OFF_ROFF);
  int* coff = (int*)(ws + OFF_COFF);
  int* bsum = (int*)(ws + OFF_BSUM);
  int* csrc = (int*)(ws + OFF_CSRC);
  int* rdst = (int*)(ws + OFF_RDST);
  int* cnt  = (int*)(ws + OFF_CNT);
  int* cur  = (int*)(ws + OFF_CUR);

  hipMemsetAsync(ws + OFF_SCAL, 0, (size_t)ZERO_FLOATS * sizeof(float), stream);

  k_detect<<<1, 256, 0, stream>>>((const unsigned int*)dm, flag);
  k_cvt<<<(CVT_TOTAL + 255) / 256, 256, 0, stream>>>(
      d_in[3], d_in[5], d_in[4], d_in[6], d_in[7], d_in[8], d_in[9],
      d_in[10], d_in[11], d_in[12], d_in[13], d_in[14], d_in[15], d_in[16],
      flag, ws);
  k_trans<<<32, 256, 0, stream>>>(ws);
  k_xdrop<<<(NN * 16 + 255) / 256, 256, 0, stream>>>(x, dm, flag, xd);
  k_hist<<<(NE + 255) / 256, 256, 0, stream>>>(ei, cnt);
  k_scanA<<<392, 256, 0, stream>>>(cnt, bsum);
  k_scanB<<<1, 256, 0, stream>>>(bsum, roff, coff);
  k_scanC<<<392, 256, 0, stream>>>(cnt, bsum, roff, coff);
  k_fill<<<(NE + 255) / 256, 256, 0, stream>>>(ei, roff, coff, cur, rdst, csrc);
  k_agg2<<<2048, 256, 0, stream>>>(coff, csrc, xd, agg);
  k_x1<<<1024, 128, 0, stream>>>(agg, xd, ws, x1);
  k_s1mm<<<(NN + 63) / 64, 256, 0, stream>>>(x1, ws, s1log);
  k_s1ln<<<1024, 256, 0, stream>>>(s1log, ws, roff, s, d_out, flag, scal);
  k_pool<<<P_POOL, 256, 0, stream>>>(s, x1, pxstsp);
  k_padj2<<<P_PADJ, 256, 0, stream>>>(roff, rdst, s, padjp);
  k_red<<<256, 256, 0, stream>>>(pxstsp, padjp, px, sts, padj);
  k_m<<<1, 256, 0, stream>>>(padj, sts, Mg, Mtg, deg2, scal);
  k_x2<<<64, 128, 0, stream>>>(Mtg, px, ws, s2g, d_out, flag);
  k_tail<<<1, 256, 0, stream>>>(Mg, s2g, deg2, scal, d_out, flag);
}

// Round 7
// 596.479 us; speedup vs baseline: 1.6267x; 1.0377x over previous
//
#include <hip/hip_runtime.h>
#include <hip/hip_bf16.h>

#define NN 50000
#define NE 800000
#define INC 64
#define HC 128
#define NC1 64
#define NC2 16

// ---- workspace layout (float offsets) ----
#define OFF_FLAG 0
#define OFW_W1R 16
#define OFW_W1O 8208
#define OFW_B1  16400
#define OFW_PW1 16528
#define OFW_PB1 24720
#define OFW_G1  24784
#define OFW_BE1 24848
#define OFW_W2R 24912
#define OFW_B2  41296
#define OFW_W2O 41424
#define OFW_PW2 57808
#define OFW_PB2 59856
#define OFW_G2  59872
#define OFW_BE2 59888
#define CVT_TOTAL 59888

#define OFW_PW1T 59904
#define OFF_MG   68096
#define OFF_MTG  72192
#define OFF_DEG2 76288
#define OFF_S2G  76352
#define OFF_COFF 77376
#define OFF_BSUM 127380
#define OFF_XD   127792
#define OFF_X1   3327792
#define OFF_S    9727792
#define OFF_AGG  12927792
#define OFF_CSRC 16127792
// ---- zero region ----
#define OFF_SCAL 16927792
#define OFF_PX   16927808
#define OFF_PADJ 16936000
#define OFF_STS  16940096
#define OFF_CNT  16944192
#define OFF_CUR  17044192
#define OFF_END  17094192
#define ZERO_FLOATS (OFF_END - OFF_SCAL)

// overlays (dead buffers reused)
#define OFF_PXSTSP OFF_XD    // 256 * 12288 = 3145728 <= 3200000 (xd dead after k_x1)
#define OFF_PADJP  OFF_X1    // 1024 * 4096 = 4194304 <= 6400000 (x1 dead after k_pool)
#define P_POOL 256
#define P_PADJ 1024

__device__ inline float bflo(unsigned int u){ return __uint_as_float(u << 16); }
__device__ inline float bfhi(unsigned int u){ return __uint_as_float(u & 0xffff0000u); }

__device__ inline float wave_sum(float v){
#pragma unroll
  for (int o = 32; o > 0; o >>= 1) v += __shfl_xor(v, o, 64);
  return v;
}
__device__ inline float wave_max(float v){
#pragma unroll
  for (int o = 32; o > 0; o >>= 1) v = fmaxf(v, __shfl_xor(v, o, 64));
  return v;
}

__device__ inline void store_out(void* out, long long idx, float v, bool bf){
  if (bf) ((__hip_bfloat16*)out)[idx] = __float2bfloat16(v);
  else    ((float*)out)[idx] = v;
}

__device__ inline float block_reduce_256(float v, float* red, int t){
  red[t] = v; __syncthreads();
#pragma unroll
  for (int sh = 128; sh > 0; sh >>= 1){
    if (t < sh) red[t] += red[t + sh];
    __syncthreads();
  }
  float r = red[0];
  __syncthreads();
  return r;
}

// K0: detect input float dtype from drop_mask bit patterns.
__global__ void k_detect(const unsigned int* __restrict__ dmw, float* __restrict__ flag){
  __shared__ int cnt;
  if (threadIdx.x == 0) cnt = 0;
  __syncthreads();
  int c = 0;
  for (int i = threadIdx.x; i < 12288; i += 256){
    unsigned int w = dmw[i];
    if (w == 0x3F803F80u || w == 0x00003F80u) c++;
  }
  atomicAdd(&cnt, c);
  __syncthreads();
  if (threadIdx.x == 0) flag[0] = (cnt > 64) ? 1.0f : 0.0f;  // 1.0 => bf16 inputs
}

// K0b: convert all weight tensors to fp32 in ws (dst = 16 + i)
__global__ void k_cvt(const void* p0, const void* p1, const void* p2, const void* p3,
                      const void* p4, const void* p5, const void* p6, const void* p7,
                      const void* p8, const void* p9, const void* p10, const void* p11,
                      const void* p12, const void* p13,
                      const float* __restrict__ flag, float* __restrict__ ws){
  int i = blockIdx.x * blockDim.x + threadIdx.x;
  if (i >= CVT_TOTAL) return;
  const void* src; int off;
  if      (i < 8192 ){ src = p0;  off = i; }
  else if (i < 16384){ src = p1;  off = i - 8192; }
  else if (i < 16512){ src = p2;  off = i - 16384; }
  else if (i < 24704){ src = p3;  off = i - 16512; }
  else if (i < 24768){ src = p4;  off = i - 24704; }
  else if (i < 24832){ src = p5;  off = i - 24768; }
  else if (i < 24896){ src = p6;  off = i - 24832; }
  else if (i < 41280){ src = p7;  off = i - 24896; }
  else if (i < 41408){ src = p8;  off = i - 41280; }
  else if (i < 57792){ src = p9;  off = i - 41408; }
  else if (i < 59840){ src = p10; off = i - 57792; }
  else if (i < 59856){ src = p11; off = i - 59840; }
  else if (i < 59872){ src = p12; off = i - 59856; }
  else               { src = p13; off = i - 59872; }
  float v = (flag[0] > 0.5f) ? __bfloat162float(((const __hip_bfloat16*)src)[off])
                             : ((const float*)src)[off];
  ws[16 + i] = v;
}

// K0c: pw1T[k*64+c] = pw1[c*128+k]  (after k_cvt)
__global__ void k_trans(float* __restrict__ ws){
  int i = blockIdx.x * blockDim.x + threadIdx.x;
  if (i < 8192){
    int k = i >> 6, c = i & 63;
    ws[OFW_PW1T + i] = ws[OFW_PW1 + c * 128 + k];
  }
}

// K1: x_drop = drop_mask[:,None] * x  -> fp32 (4 elems/thread)
__global__ void k_xdrop(const void* __restrict__ xr, const void* __restrict__ dmr,
                        const float* __restrict__ flag, float* __restrict__ xd){
  int i4 = blockIdx.x * blockDim.x + threadIdx.x;
  if (i4 >= NN * 16) return;
  int n = i4 >> 4;
  float4 o;
  if (flag[0] > 0.5f){
    uint2 w = ((const uint2*)xr)[i4];
    float dv = __bfloat162float(((const __hip_bfloat16*)dmr)[n]);
    o.x = bflo(w.x) * dv; o.y = bfhi(w.x) * dv;
    o.z = bflo(w.y) * dv; o.w = bfhi(w.y) * dv;
  } else {
    float4 xv = ((const float4*)xr)[i4];
    float dv = ((const float*)dmr)[n];
    o.x = xv.x * dv; o.y = xv.y * dv; o.z = xv.z * dv; o.w = xv.w * dv;
  }
  ((float4*)xd)[i4] = o;
}

// ---- CSR build (col direction only; row-degree kept in cnt histogram) ----
__global__ void k_hist(const int* __restrict__ ei, int* __restrict__ cnt){
  int e = blockIdx.x * blockDim.x + threadIdx.x;
  if (e < NE){
    atomicAdd(&cnt[ei[e]], 1);            // row (for deg)
    atomicAdd(&cnt[NN + ei[NE + e]], 1);  // col (for CSR)
  }
}

__global__ __launch_bounds__(256) void k_scanA(const int* __restrict__ cnt,
                                               int* __restrict__ bsum){
  __shared__ int red[256];
  int b = blockIdx.x;          // 0..195
  int i = b * 256 + threadIdx.x;
  int v = (i < NN) ? cnt[NN + i] : 0;
  red[threadIdx.x] = v; __syncthreads();
#pragma unroll
  for (int sh = 128; sh > 0; sh >>= 1){
    if (threadIdx.x < sh) red[threadIdx.x] += red[threadIdx.x + sh];
    __syncthreads();
  }
  if (threadIdx.x == 0) bsum[b] = red[0];
}

__global__ __launch_bounds__(256) void k_scanB(int* __restrict__ bsum,
                                               int* __restrict__ coff){
  __shared__ int sh[256];
  int t = threadIdx.x;
  int v = (t < 196) ? bsum[t] : 0;
  sh[t] = v; __syncthreads();
  for (int o = 1; o < 256; o <<= 1){
    int x = (t >= o) ? sh[t - o] : 0;
    __syncthreads();
    sh[t] += x;
    __syncthreads();
  }
  if (t < 196) bsum[t] = sh[t] - v;   // exclusive
  if (t == 0) coff[NN] = NE;
}

__global__ __launch_bounds__(256) void k_scanC(const int* __restrict__ cnt,
                                               const int* __restrict__ bsum,
                                               int* __restrict__ coff){
  __shared__ int sh[256];
  int b = blockIdx.x, t = threadIdx.x;
  int i = b * 256 + t;
  int v = (i < NN) ? cnt[NN + i] : 0;
  sh[t] = v; __syncthreads();
  for (int o = 1; o < 256; o <<= 1){
    int x = (t >= o) ? sh[t - o] : 0;
    __syncthreads();
    sh[t] += x;
    __syncthreads();
  }
  int excl = sh[t] - v + bsum[b];
  if (i < NN) coff[i] = excl;
}

__global__ void k_fill(const int* __restrict__ ei, const int* __restrict__ coff,
                       int* __restrict__ cur, int* __restrict__ csrc){
  int e = blockIdx.x * blockDim.x + threadIdx.x;
  if (e < NE){
    int r = ei[e], c = ei[NE + e];
    int pc = coff[c] + atomicAdd(&cur[c], 1);
    csrc[pc] = r;
  }
}

// ---- lane-parallel CSR row-gather: sum_{e in [st,en)} table[idx[e]] (64-float rows)
__device__ inline float4 gather_rowsum(const int* __restrict__ idxarr, int st, int en,
                                       const float* __restrict__ table, int lane,
                                       int g, int sub){
  float4 a0 = {0,0,0,0}, a1 = {0,0,0,0}, a2 = {0,0,0,0}, a3 = {0,0,0,0};
  for (int bb = st; bb < en; bb += 64){
    int rem = en - bb;
    int myi = (bb + lane < en) ? idxarr[bb + lane] : 0;
    int niter = ((rem < 64 ? rem : 64) + 3) >> 2;
    int i = 0;
    for (; i + 4 <= niter; i += 4){
      int s0 = __shfl(myi, g + ((i    ) << 2), 64);
      int s1 = __shfl(myi, g + ((i + 1) << 2), 64);
      int s2 = __shfl(myi, g + ((i + 2) << 2), 64);
      int s3 = __shfl(myi, g + ((i + 3) << 2), 64);
      if ((g + (i << 2))       < rem){ float4 v = *(const float4*)(table + (s0 << 6) + (sub << 2)); a0.x += v.x; a0.y += v.y; a0.z += v.z; a0.w += v.w; }
      if ((g + ((i + 1) << 2)) < rem){ float4 v = *(const float4*)(table + (s1 << 6) + (sub << 2)); a1.x += v.x; a1.y += v.y; a1.z += v.z; a1.w += v.w; }
      if ((g + ((i + 2) << 2)) < rem){ float4 v = *(const float4*)(table + (s2 << 6) + (sub << 2)); a2.x += v.x; a2.y += v.y; a2.z += v.z; a2.w += v.w; }
      if ((g + ((i + 3) << 2)) < rem){ float4 v = *(const float4*)(table + (s3 << 6) + (sub << 2)); a3.x += v.x; a3.y += v.y; a3.z += v.z; a3.w += v.w; }
    }
    for (; i < niter; ++i){
      int slot = g + (i << 2);
      int s0 = __shfl(myi, slot, 64);
      if (slot < rem){ float4 v = *(const float4*)(table + (s0 << 6) + (sub << 2)); a0.x += v.x; a0.y += v.y; a0.z += v.z; a0.w += v.w; }
    }
  }
  float4 a;
  a.x = (a0.x + a1.x) + (a2.x + a3.x);
  a.y = (a0.y + a1.y) + (a2.y + a3.y);
  a.z = (a0.z + a1.z) + (a2.z + a3.z);
  a.w = (a0.w + a1.w) + (a2.w + a3.w);
  a.x += __shfl_xor(a.x, 16, 64); a.x += __shfl_xor(a.x, 32, 64);
  a.y += __shfl_xor(a.y, 16, 64); a.y += __shfl_xor(a.y, 32, 64);
  a.z += __shfl_xor(a.z, 16, 64); a.z += __shfl_xor(a.z, 32, 64);
  a.w += __shfl_xor(a.w, 16, 64); a.w += __shfl_xor(a.w, 32, 64);
  return a;
}

// K2: agg[n] = sum_{e: col=n} xd[csrc[e]]
__global__ __launch_bounds__(256) void k_agg2(const int* __restrict__ coff,
                                              const int* __restrict__ csrc,
                                              const float* __restrict__ xd,
                                              float* __restrict__ agg){
  int gid = blockIdx.x * 256 + threadIdx.x;
  int lane = gid & 63, wid = gid >> 6;
  int nw = (gridDim.x * 256) >> 6;
  int g = lane >> 4, sub = lane & 15;
  for (int n = wid; n < NN; n += nw){
    int st = coff[n], en = coff[n + 1];
    float4 a = gather_rowsum(csrc, st, en, xd, lane, g, sub);
    if (g == 0) *(float4*)(agg + (n << 6) + (sub << 2)) = a;
  }
}

// K3: x1 = relu(agg @ W1_rel^T + b1 + x_drop @ W1_root^T), 8-node batches
__global__ __launch_bounds__(128) void k_x1(const float* __restrict__ agg,
                                            const float* __restrict__ xd,
                                            const float* __restrict__ wts,
                                            float* __restrict__ x1){
  __shared__ float nb[8][2][64];
  int t = threadIdx.x;
  float wr[64], wo[64];
#pragma unroll
  for (int j = 0; j < 64; ++j){
    wr[j] = wts[OFW_W1R + t * 64 + j];
    wo[j] = wts[OFW_W1O + t * 64 + j];
  }
  float bias = wts[OFW_B1 + t];
  const int nbatch = NN / 8;   // 6250
  for (int b = blockIdx.x; b < nbatch; b += gridDim.x){
    int base = b * 8;
#pragma unroll
    for (int i = 0; i < 2; ++i){
      int f = t + (i << 7);
      int u = f >> 5;
      int j = f & 31;
      const float* src = (j < 16) ? (agg + ((base + u) << 6) + (j << 2))
                                  : (xd  + ((base + u) << 6) + ((j - 16) << 2));
      *(float4*)&nb[u][j >> 4][(j & 15) << 2] = *(const float4*)src;
    }
    __syncthreads();
#pragma unroll
    for (int u = 0; u < 8; ++u){
      float acc_a = bias, acc_x = 0.0f;
#pragma unroll
      for (int j = 0; j < 16; ++j){
        float4 va = *(const float4*)&nb[u][0][j << 2];
        float4 vx = *(const float4*)&nb[u][1][j << 2];
        acc_a += va.x * wr[4*j] + va.y * wr[4*j+1] + va.z * wr[4*j+2] + va.w * wr[4*j+3];
        acc_x += vx.x * wo[4*j] + vx.y * wo[4*j+1] + vx.z * wo[4*j+2] + vx.w * wo[4*j+3];
      }
      x1[(base + u) * HC + t] = fmaxf(acc_a + acc_x, 0.0f);
    }
    __syncthreads();
  }
}

// K4: fused s1 = LN(x1 @ pW1^T + pb1) -> softmax/log_softmax, per-64-node tile.
// GEMM phase (4x4 reg tiles) then in-block LN/softmax via wave ops; logits
// round-trip through the (dead) xs LDS tile. deg from cnt row-histogram.
__global__ __launch_bounds__(256) void k_s1f(const float* __restrict__ x1,
                                             const float* __restrict__ wts,
                                             const int* __restrict__ cnt,
                                             float* __restrict__ s,
                                             void* __restrict__ outp,
                                             const float* __restrict__ flag,
                                             float* __restrict__ scal){
  __shared__ float xs[64 * 129];     // x1 tile, then logit tile (stride 129)
  __shared__ float pwsh[HC * 64];    // [k][c]
  __shared__ float gsh[64], bsh[64];
  __shared__ float wden[4];
  int t = threadIdx.x;
  int base = blockIdx.x * 64;
  for (int i = t; i < HC * 64; i += 256) pwsh[i] = wts[OFW_PW1T + i];
  if (t < 64){ gsh[t] = wts[OFW_G1 + t]; bsh[t] = wts[OFW_BE1 + t]; }
  for (int f = t; f < 64 * 32; f += 256){
    int r = f >> 5, kq = f & 31;
    float4 v = (base + r < NN) ? *(const float4*)(x1 + (base + r) * HC + (kq << 2))
                               : make_float4(0, 0, 0, 0);
    xs[r * 129 + 4*kq]     = v.x;
    xs[r * 129 + 4*kq + 1] = v.y;
    xs[r * 129 + 4*kq + 2] = v.z;
    xs[r * 129 + 4*kq + 3] = v.w;
  }
  __syncthreads();
  int ni = t >> 4, cj = t & 15;
  float4 c0 = {0,0,0,0}, c1 = {0,0,0,0}, c2 = {0,0,0,0}, c3 = {0,0,0,0};
#pragma unroll 4
  for (int k = 0; k < HC; ++k){
    float4 b = *(const float4*)&pwsh[k * 64 + (cj << 2)];
    float a0 = xs[(ni * 4 + 0) * 129 + k];
    float a1 = xs[(ni * 4 + 1) * 129 + k];
    float a2 = xs[(ni * 4 + 2) * 129 + k];
    float a3 = xs[(ni * 4 + 3) * 129 + k];
    c0.x += a0 * b.x; c0.y += a0 * b.y; c0.z += a0 * b.z; c0.w += a0 * b.w;
    c1.x += a1 * b.x; c1.y += a1 * b.y; c1.z += a1 * b.z; c1.w += a1 * b.w;
    c2.x += a2 * b.x; c2.y += a2 * b.y; c2.z += a2 * b.z; c2.w += a2 * b.w;
    c3.x += a3 * b.x; c3.y += a3 * b.y; c3.z += a3 * b.z; c3.w += a3 * b.w;
  }
  float4 pb = *(const float4*)&wts[OFW_PB1 + (cj << 2)];
  c0.x += pb.x; c0.y += pb.y; c0.z += pb.z; c0.w += pb.w;
  c1.x += pb.x; c1.y += pb.y; c1.z += pb.z; c1.w += pb.w;
  c2.x += pb.x; c2.y += pb.y; c2.z += pb.z; c2.w += pb.w;
  c3.x += pb.x; c3.y += pb.y; c3.z += pb.z; c3.w += pb.w;
  __syncthreads();   // all xs reads done; now overwrite with logits
  {
    int col = cj << 2;
    float* r0 = &xs[(ni * 4 + 0) * 129 + col];
    float* r1 = &xs[(ni * 4 + 1) * 129 + col];
    float* r2 = &xs[(ni * 4 + 2) * 129 + col];
    float* r3 = &xs[(ni * 4 + 3) * 129 + col];
    r0[0] = c0.x; r0[1] = c0.y; r0[2] = c0.z; r0[3] = c0.w;
    r1[0] = c1.x; r1[1] = c1.y; r1[2] = c1.z; r1[3] = c1.w;
    r2[0] = c2.x; r2[1] = c2.y; r2[2] = c2.z; r2[3] = c2.w;
    r3[0] = c3.x; r3[1] = c3.y; r3[2] = c3.z; r3[3] = c3.w;
  }
  __syncthreads();
  bool bf = flag[0] > 0.5f;
  int lane = t & 63, wv = t >> 6;
  float dacc = 0.0f;
  for (int rr = 0; rr < 16; ++rr){
    int row = wv * 16 + rr;
    int n = base + row;
    if (n >= NN) break;
    float z = xs[row * 129 + lane];
    float mu  = wave_sum(z) * (1.0f / 64.0f);
    float d   = z - mu;
    float var = wave_sum(d * d) * (1.0f / 64.0f);
    float y   = d * rsqrtf(var + 1e-5f) * gsh[lane] + bsh[lane];
    float m   = wave_max(y);
    float ex  = expf(y - m);
    float se  = wave_sum(ex);
    float sv  = ex / se;
    s[n * 64 + lane] = sv;
    store_out(outp, 4LL + (long long)n * 64 + lane, (y - m) - logf(se), bf);
    dacc += (float)cnt[n] * sv * sv;
  }
  float wsum = wave_sum(dacc);
  if (lane == 0) wden[wv] = wsum;
  __syncthreads();
  if (t == 0) atomicAdd(&scal[0], wden[0] + wden[1] + wden[2] + wden[3]);
}

// K5: padj partials via col-CSR: padj = sum_n asCol[n] (x) s[n],
//     asCol[n] = sum_{e: col=n} s[csrc[e]]  (gathered -> i side; s[n] -> j side)
__global__ __launch_bounds__(256) void k_padj2(const int* __restrict__ coff,
                                               const int* __restrict__ csrc,
                                               const float* __restrict__ s,
                                               float* __restrict__ padjp){
  __shared__ float rs[16 * 64];   // i-side (gathered asCol)
  __shared__ float ra[16 * 64];   // j-side (s[n])
  int t = threadIdx.x, lane = t & 63, w = t >> 6;
  int g = lane >> 4, sub = lane & 15;
  int i4 = t >> 4;
  int j4 = t & 15;
  float4 acc0 = {0,0,0,0}, acc1 = {0,0,0,0}, acc2 = {0,0,0,0}, acc3 = {0,0,0,0};
  const int nbatch = NN / 16;   // 3125
  for (int b = blockIdx.x; b < nbatch; b += gridDim.x){
    int base = b * 16;
#pragma unroll
    for (int q = 0; q < 4; ++q){
      int k = w * 4 + q;
      int n = base + k;
      int st = coff[n], en = coff[n + 1];
      float4 a = gather_rowsum(csrc, st, en, s, lane, g, sub);
      if (g == 0){
        *(float4*)&rs[k * 64 + (sub << 2)] = a;
      } else if (g == 1){
        *(float4*)&ra[k * 64 + (sub << 2)] = *(const float4*)(s + (n << 6) + (sub << 2));
      }
    }
    __syncthreads();
#pragma unroll
    for (int k = 0; k < 16; ++k){
      float4 a  = *(const float4*)&rs[k * 64 + (i4 << 2)];
      float4 bv = *(const float4*)&ra[k * 64 + (j4 << 2)];
      acc0.x += a.x * bv.x; acc0.y += a.x * bv.y; acc0.z += a.x * bv.z; acc0.w += a.x * bv.w;
      acc1.x += a.y * bv.x; acc1.y += a.y * bv.y; acc1.z += a.y * bv.z; acc1.w += a.y * bv.w;
      acc2.x += a.z * bv.x; acc2.y += a.z * bv.y; acc2.z += a.z * bv.z; acc2.w += a.z * bv.w;
      acc3.x += a.w * bv.x; acc3.y += a.w * bv.y; acc3.z += a.w * bv.z; acc3.w += a.w * bv.w;
    }
    __syncthreads();
  }
  float* pp = padjp + blockIdx.x * 4096;
  *(float4*)&pp[(i4 * 4 + 0) * 64 + (j4 << 2)] = acc0;
  *(float4*)&pp[(i4 * 4 + 1) * 64 + (j4 << 2)] = acc1;
  *(float4*)&pp[(i4 * 4 + 2) * 64 + (j4 << 2)] = acc2;
  *(float4*)&pp[(i4 * 4 + 3) * 64 + (j4 << 2)] = acc3;
}

// K6: px/sts partials. 32-node batches, float4 staged, conflict-free interleaved cols.
__global__ __launch_bounds__(256) void k_pool(const float* __restrict__ s,
                                              const float* __restrict__ x1,
                                              float* __restrict__ part){
  __shared__ float ssh[32 * 64];
  __shared__ float xsh[32 * 128];
  int t = threadIdx.x;
  int c = t >> 2, q = t & 3;
  float4 apx[8], ast[4];
#pragma unroll
  for (int m = 0; m < 8; ++m) apx[m] = make_float4(0, 0, 0, 0);
#pragma unroll
  for (int m = 0; m < 4; ++m) ast[m] = make_float4(0, 0, 0, 0);
  const int nbatch = (NN + 31) / 32;
  for (int b = blockIdx.x; b < nbatch; b += gridDim.x){
    int base = b * 32;
    int kmax = NN - base; if (kmax > 32) kmax = 32;
#pragma unroll
    for (int i = 0; i < 2; ++i){
      int f = t + (i << 8);
      int k = f >> 4, col = f & 15;
      float4 v = (k < kmax) ? *(const float4*)(s + ((base + k) << 6) + (col << 2))
                            : make_float4(0, 0, 0, 0);
      *(float4*)&ssh[k * 64 + (col << 2)] = v;
    }
#pragma unroll
    for (int i = 0; i < 4; ++i){
      int f = t + (i << 8);
      int k = f >> 5, col = f & 31;
      float4 v = (k < kmax) ? *(const float4*)(x1 + (base + k) * HC + (col << 2))
                            : make_float4(0, 0, 0, 0);
      *(float4*)&xsh[k * 128 + (col << 2)] = v;
    }
    __syncthreads();
    for (int k = 0; k < kmax; ++k){
      float sv = ssh[k * 64 + c];
#pragma unroll
      for (int m = 0; m < 8; ++m){
        float4 xv = *(const float4*)&xsh[k * 128 + m * 16 + (q << 2)];
        apx[m].x += sv * xv.x; apx[m].y += sv * xv.y;
        apx[m].z += sv * xv.z; apx[m].w += sv * xv.w;
      }
#pragma unroll
      for (int m = 0; m < 4; ++m){
        float4 v2 = *(const float4*)&ssh[k * 64 + m * 16 + (q << 2)];
        ast[m].x += sv * v2.x; ast[m].y += sv * v2.y;
        ast[m].z += sv * v2.z; ast[m].w += sv * v2.w;
      }
    }
    __syncthreads();
  }
  float* pp = part + blockIdx.x * 12288;
#pragma unroll
  for (int m = 0; m < 8; ++m)
    *(float4*)&pp[c * 128 + m * 16 + (q << 2)] = apx[m];
#pragma unroll
  for (int m = 0; m < 4; ++m)
    *(float4*)&pp[8192 + c * 64 + m * 16 + (q << 2)] = ast[m];
}

// K6b: reduce partials -> px, sts (192 blocks) and padj (64 blocks). grid=256.
__global__ __launch_bounds__(256) void k_red(const float* __restrict__ pxstsp,
                                             const float* __restrict__ padjp,
                                             float* __restrict__ px,
                                             float* __restrict__ sts,
                                             float* __restrict__ padj){
  __shared__ float sh[256];
  int b = blockIdx.x, t = threadIdx.x;
  int ci = t & 63, pc = t >> 6;
  if (b < 192){
    int cell = b * 64 + ci;
    float a0 = 0, a1 = 0, a2 = 0, a3 = 0;
    const float* basep = pxstsp + cell;
    int p0 = pc * (P_POOL / 4);
    for (int p = 0; p < P_POOL / 4; p += 4){
      a0 += basep[(p0 + p    ) * 12288];
      a1 += basep[(p0 + p + 1) * 12288];
      a2 += basep[(p0 + p + 2) * 12288];
      a3 += basep[(p0 + p + 3) * 12288];
    }
    sh[t] = (a0 + a1) + (a2 + a3);
    __syncthreads();
    if (t < 64){
      float r = sh[t] + sh[t + 64] + sh[t + 128] + sh[t + 192];
      int cell2 = b * 64 + t;
      if (cell2 < 8192) px[cell2] = r; else sts[cell2 - 8192] = r;
    }
  } else {
    int cell = (b - 192) * 64 + ci;
    float a0 = 0, a1 = 0, a2 = 0, a3 = 0;
    const float* basep = padjp + cell;
    int p0 = pc * (P_PADJ / 4);
    for (int p = 0; p < P_PADJ / 4; p += 4){
      a0 += basep[(p0 + p    ) * 4096];
      a1 += basep[(p0 + p + 1) * 4096];
      a2 += basep[(p0 + p + 2) * 4096];
      a3 += basep[(p0 + p + 3) * 4096];
    }
    sh[t] = (a0 + a1) + (a2 + a3);
    __syncthreads();
    if (t < 64) padj[(b - 192) * 64 + t] = sh[t] + sh[t + 64] + sh[t + 128] + sh[t + 192];
  }
}

// K7a: M, Mt, deg2, num1(trace), o1
__global__ __launch_bounds__(256) void k_m(const float* __restrict__ padj,
                                           const float* __restrict__ sts,
                                           float* __restrict__ Mg,
                                           float* __restrict__ Mtg,
                                           float* __restrict__ deg2,
                                           float* __restrict__ scal){
  __shared__ float red[256];
  __shared__ float psh[4096];
  __shared__ float dsi[64];
  int t = threadIdx.x;
  const float TH = 1.0f / 63.0f;
  for (int i = t; i < 4096; i += 256) psh[i] = padj[i];
  __syncthreads();
  float v = (t < 64) ? psh[t * 65] : 0.0f;
  float num1 = block_reduce_256(v, red, t);
  v = 0.0f;
  for (int i = t; i < 4096; i += 256){ float e = sts[i]; v += e * e; }
  float nrm1 = sqrtf(block_reduce_256(v, red, t));
  v = 0.0f;
  for (int i = t; i < 4096; i += 256){
    float e = sts[i] / (nrm1 + 1e-10f) - ((i % 65 == 0) ? 0.125f : 0.0f);
    v += e * e;
  }
  float o1 = sqrtf(block_reduce_256(v, red, t));
  if (t < 64){
    float rs = 0.0f;
    for (int j = 0; j < 64; ++j) rs += (j == t) ? 0.0f : psh[t * 64 + j];
    dsi[t] = 1.0f / (sqrtf(rs) + 1e-15f);
  }
  __syncthreads();
  for (int i = t; i < 4096; i += 256){
    int r = i >> 6, c = i & 63;
    float a = (r == c) ? 0.0f : psh[i];
    float m = (a * dsi[r] * dsi[c] > TH) ? 1.0f : 0.0f;
    Mg[i] = m;
    Mtg[c * 64 + r] = m;
  }
  __syncthreads();
  for (int i = t; i < 4096; i += 256){
    int r = i >> 6, c = i & 63;
    float a = (r == c) ? 0.0f : psh[i];
    psh[i] = (a * dsi[r] * dsi[c] > TH) ? 1.0f : 0.0f;
  }
  __syncthreads();
  if (t < 64){
    float d2 = 0.0f;
    for (int j = 0; j < 64; ++j) d2 += psh[t * 64 + j];
    deg2[t] = d2;
  }
  if (t == 0){ scal[1] = num1; scal[2] = o1; }
}

// K7b: per-cluster fused mp/x2/s2-logits/LN/softmax (64 blocks x 128 thr)
__global__ __launch_bounds__(128) void k_x2(const float* __restrict__ Mtg,
                                            const float* __restrict__ px,
                                            const float* __restrict__ wts,
                                            float* __restrict__ s2g,
                                            void* __restrict__ out,
                                            const float* __restrict__ flag){
  __shared__ float mt[64], pxc[128], mpsh[128], x2sh[128];
  __shared__ float part[16][9], lsh[16], stat[2];
  int c = blockIdx.x, t = threadIdx.x;
  if (t < 64) mt[t] = Mtg[c * 64 + t];
  pxc[t] = px[c * 128 + t];
  __syncthreads();
  float mp = 0.0f;
  for (int i = 0; i < 64; ++i) mp += mt[i] * px[i * 128 + t];
  mpsh[t] = mp;
  __syncthreads();
  float acc = wts[OFW_B2 + t];
  const float* wrr = wts + OFW_W2R + t * 128;
  const float* wor = wts + OFW_W2O + t * 128;
  for (int k = 0; k < 128; ++k) acc += mpsh[k] * wrr[k] + pxc[k] * wor[k];
  x2sh[t] = fmaxf(acc, 0.0f);
  __syncthreads();
  { int u = t >> 3, p = t & 7;
    const float* pw = wts + OFW_PW2 + u * 128 + p * 16;
    float pa = 0.0f;
    for (int k = 0; k < 16; ++k) pa += x2sh[p * 16 + k] * pw[k];
    part[u][p] = pa;
  }
  __syncthreads();
  if (t < 16){
    float l = wts[OFW_PB2 + t];
    for (int p = 0; p < 8; ++p) l += part[t][p];
    lsh[t] = l;
  }
  __syncthreads();
  if (t == 0){
    float mu = 0.0f;
    for (int u = 0; u < 16; ++u) mu += lsh[u];
    mu *= (1.0f / 16.0f);
    float var = 0.0f;
    for (int u = 0; u < 16; ++u){ float d = lsh[u] - mu; var += d * d; }
    var *= (1.0f / 16.0f);
    float rstd = rsqrtf(var + 1e-5f);
    float m = -3.4e38f;
    for (int u = 0; u < 16; ++u){
      lsh[u] = (lsh[u] - mu) * rstd * wts[OFW_G2 + u] + wts[OFW_BE2 + u];
      m = fmaxf(m, lsh[u]);
    }
    float se = 0.0f;
    for (int u = 0; u < 16; ++u) se += expf(lsh[u] - m);
    stat[0] = m; stat[1] = logf(se);
  }
  __syncthreads();
  if (t < 16){
    float ls = (lsh[t] - stat[0]) - stat[1];
    store_out(out, 4LL + (long long)NN * NC1 + c * 16 + t, ls, flag[0] > 0.5f);
    s2g[c * 16 + t] = expf(ls);
  }
}

// K7c: mc2 / o2 tail (1 block)
__global__ __launch_bounds__(256) void k_tail(const float* __restrict__ Mg,
                                              const float* __restrict__ s2g,
                                              const float* __restrict__ deg2,
                                              const float* __restrict__ scal,
                                              void* __restrict__ out,
                                              const float* __restrict__ flag){
  __shared__ float red[256];
  __shared__ float Msh[4096];
  __shared__ float s2sh[1024];
  __shared__ float d2sh[64];
  __shared__ float sts2[256];
  int t = threadIdx.x;
  for (int i = t; i < 4096; i += 256) Msh[i] = Mg[i];
  for (int i = t; i < 1024; i += 256) s2sh[i] = s2g[i];
  if (t < 64) d2sh[t] = deg2[t];
  __syncthreads();
  float vnum = 0.0f, vden = 0.0f;
  for (int m = 0; m < 4; ++m){
    int id = t + m * 256;
    int c = id >> 4, u = id & 15;
    float a = 0.0f;
    for (int j = 0; j < 64; ++j) a += Msh[c * 64 + j] * s2sh[j * 16 + u];
    float sv = s2sh[id];
    vnum += sv * a;
    vden += d2sh[c] * sv * sv;
  }
  float num2 = block_reduce_256(vnum, red, t);
  float den2 = block_reduce_256(vden, red, t) + 1e-10f;
  { int u = t >> 4, w = t & 15;
    float a = 0.0f;
    for (int c2 = 0; c2 < 64; ++c2) a += s2sh[c2 * 16 + u] * s2sh[c2 * 16 + w];
    sts2[t] = a;
  }
  __syncthreads();
  float v = sts2[t] * sts2[t];
  float nrm2 = sqrtf(block_reduce_256(v, red, t));
  { float e = sts2[t] / (nrm2 + 1e-10f) - (((t >> 4) == (t & 15)) ? 0.25f : 0.0f);
    v = e * e; }
  float o2 = sqrtf(block_reduce_256(v, red, t));
  if (t == 0){
    bool bf = flag[0] > 0.5f;
    float den = scal[0] + 1e-10f;
    store_out(out, 0, -scal[1] / den, bf);
    store_out(out, 1, scal[2], bf);
    store_out(out, 2, -num2 / den2, bf);
    store_out(out, 3, o2, bf);
  }
}

extern "C" void kernel_launch(void* const* d_in, const int* in_sizes, int n_in,
                              void* d_out, int out_size, void* d_ws, size_t ws_size,
                              hipStream_t stream){
  const void* x  = d_in[0];
  const int*  ei = (const int*)d_in[1];
  const void* dm = d_in[2];

  float* ws    = (float*)d_ws;
  float* flag  = ws + OFF_FLAG;
  float* xd    = ws + OFF_XD;
  float* x1    = ws + OFF_X1;
  float* s     = ws + OFF_S;
  float* agg   = ws + OFF_AGG;
  float* px    = ws + OFF_PX;
  float* padj  = ws + OFF_PADJ;
  float* sts   = ws + OFF_STS;
  float* scal  = ws + OFF_SCAL;
  float* Mg    = ws + OFF_MG;
  float* Mtg   = ws + OFF_MTG;
  float* deg2  = ws + OFF_DEG2;
  float* s2g   = ws + OFF_S2G;
  float* pxstsp= ws + OFF_PXSTSP;
  float* padjp = ws + OFF_PADJP;
  int* coff = (int*)(ws + OFF_COFF);
  int* bsum = (int*)(ws + OFF_BSUM);
  int* csrc = (int*)(ws + OFF_CSRC);
  int* cnt  = (int*)(ws + OFF_CNT);
  int* cur  = (int*)(ws + OFF_CUR);

  hipMemsetAsync(ws + OFF_SCAL, 0, (size_t)ZERO_FLOATS * sizeof(float), stream);

  k_detect<<<1, 256, 0, stream>>>((const unsigned int*)dm, flag);
  k_cvt<<<(CVT_TOTAL + 255) / 256, 256, 0, stream>>>(
      d_in[3], d_in[5], d_in[4], d_in[6], d_in[7], d_in[8], d_in[9],
      d_in[10], d_in[11], d_in[12], d_in[13], d_in[14], d_in[15], d_in[16],
      flag, ws);
  k_trans<<<32, 256, 0, stream>>>(ws);
  k_xdrop<<<(NN * 16 + 255) / 256, 256, 0, stream>>>(x, dm, flag, xd);
  k_hist<<<(NE + 255) / 256, 256, 0, stream>>>(ei, cnt);
  k_scanA<<<196, 256, 0, stream>>>(cnt, bsum);
  k_scanB<<<1, 256, 0, stream>>>(bsum, coff);
  k_scanC<<<196, 256, 0, stream>>>(cnt, bsum, coff);
  k_fill<<<(NE + 255) / 256, 256, 0, stream>>>(ei, coff, cur, csrc);
  k_agg2<<<2048, 256, 0, stream>>>(coff, csrc, xd, agg);
  k_x1<<<2048, 128, 0, stream>>>(agg, xd, ws, x1);
  k_s1f<<<(NN + 63) / 64, 256, 0, stream>>>(x1, ws, cnt, s, d_out, flag, scal);
  k_pool<<<P_POOL, 256, 0, stream>>>(s, x1, pxstsp);
  k_padj2<<<P_PADJ, 256, 0, stream>>>(coff, csrc, s, padjp);
  k_red<<<256, 256, 0, stream>>>(pxstsp, padjp, px, sts, padj);
  k_m<<<1, 256, 0, stream>>>(padj, sts, Mg, Mtg, deg2, scal);
  k_x2<<<64, 128, 0, stream>>>(Mtg, px, ws, s2g, d_out, flag);
  k_tail<<<1, 256, 0, stream>>>(Mg, s2g, deg2, scal, d_out, flag);
}

// Round 8
// 538.696 us; speedup vs baseline: 1.8012x; 1.1073x over previous
//
#include <hip/hip_runtime.h>
#include <hip/hip_bf16.h>

#define NN 50000
#define NE 800000
#define INC 64
#define HC 128
#define NC1 64
#define NC2 16

// ---- workspace layout (float offsets) ----
#define OFF_FLAG 0
#define OFW_W1R 16
#define OFW_W1O 8208
#define OFW_B1  16400
#define OFW_PW1 16528
#define OFW_PB1 24720
#define OFW_G1  24784
#define OFW_BE1 24848
#define OFW_W2R 24912
#define OFW_B2  41296
#define OFW_W2O 41424
#define OFW_PW2 57808
#define OFW_PB2 59856
#define OFW_G2  59872
#define OFW_BE2 59888
#define CVT_TOTAL 59888

#define OFW_PW1T 59904
#define OFF_MG   68096
#define OFF_MTG  72192
#define OFF_DEG2 76288
#define OFF_S2G  76352
#define OFF_COFF 77376
#define OFF_BSUM 127380
#define OFF_XD   127792
#define OFF_X1   3327792
#define OFF_S    9727792
#define OFF_AGG  12927792
#define OFF_CSRC 16127792
// ---- zero region ----
#define OFF_SCAL 16927792
#define OFF_PX   16927808
#define OFF_PADJ 16936000
#define OFF_STS  16940096
#define OFF_CNT  16944192
#define OFF_CUR  17044192
#define OFF_END  17094192
#define ZERO_FLOATS (OFF_END - OFF_SCAL)

// overlays (dead buffers reused)
#define OFF_PXSTSP OFF_XD    // 256 * 12288 = 3145728 <= 3200000 (xd dead after k_x1)
#define OFF_PADJP  OFF_X1    // 1024 * 4096 = 4194304 <= 6400000 (x1 dead after k_pool)
#define P_POOL 256
#define P_PADJ 1024

__device__ inline float bflo(unsigned int u){ return __uint_as_float(u << 16); }
__device__ inline float bfhi(unsigned int u){ return __uint_as_float(u & 0xffff0000u); }

__device__ inline float wave_sum(float v){
#pragma unroll
  for (int o = 32; o > 0; o >>= 1) v += __shfl_xor(v, o, 64);
  return v;
}
__device__ inline float wave_max(float v){
#pragma unroll
  for (int o = 32; o > 0; o >>= 1) v = fmaxf(v, __shfl_xor(v, o, 64));
  return v;
}

__device__ inline void store_out(void* out, long long idx, float v, bool bf){
  if (bf) ((__hip_bfloat16*)out)[idx] = __float2bfloat16(v);
  else    ((float*)out)[idx] = v;
}

__device__ inline float block_reduce_256(float v, float* red, int t){
  red[t] = v; __syncthreads();
#pragma unroll
  for (int sh = 128; sh > 0; sh >>= 1){
    if (t < sh) red[t] += red[t + sh];
    __syncthreads();
  }
  float r = red[0];
  __syncthreads();
  return r;
}

// K0: detect input float dtype from drop_mask bit patterns.
__global__ void k_detect(const unsigned int* __restrict__ dmw, float* __restrict__ flag){
  __shared__ int cnt;
  if (threadIdx.x == 0) cnt = 0;
  __syncthreads();
  int c = 0;
  for (int i = threadIdx.x; i < 12288; i += 256){
    unsigned int w = dmw[i];
    if (w == 0x3F803F80u || w == 0x00003F80u) c++;
  }
  atomicAdd(&cnt, c);
  __syncthreads();
  if (threadIdx.x == 0) flag[0] = (cnt > 64) ? 1.0f : 0.0f;  // 1.0 => bf16 inputs
}

// K0b: convert all weight tensors to fp32 in ws (dst = 16 + i)
__global__ void k_cvt(const void* p0, const void* p1, const void* p2, const void* p3,
                      const void* p4, const void* p5, const void* p6, const void* p7,
                      const void* p8, const void* p9, const void* p10, const void* p11,
                      const void* p12, const void* p13,
                      const float* __restrict__ flag, float* __restrict__ ws){
  int i = blockIdx.x * blockDim.x + threadIdx.x;
  if (i >= CVT_TOTAL) return;
  const void* src; int off;
  if      (i < 8192 ){ src = p0;  off = i; }
  else if (i < 16384){ src = p1;  off = i - 8192; }
  else if (i < 16512){ src = p2;  off = i - 16384; }
  else if (i < 24704){ src = p3;  off = i - 16512; }
  else if (i < 24768){ src = p4;  off = i - 24704; }
  else if (i < 24832){ src = p5;  off = i - 24768; }
  else if (i < 24896){ src = p6;  off = i - 24832; }
  else if (i < 41280){ src = p7;  off = i - 24896; }
  else if (i < 41408){ src = p8;  off = i - 41280; }
  else if (i < 57792){ src = p9;  off = i - 41408; }
  else if (i < 59840){ src = p10; off = i - 57792; }
  else if (i < 59856){ src = p11; off = i - 59840; }
  else if (i < 59872){ src = p12; off = i - 59856; }
  else               { src = p13; off = i - 59872; }
  float v = (flag[0] > 0.5f) ? __bfloat162float(((const __hip_bfloat16*)src)[off])
                             : ((const float*)src)[off];
  ws[16 + i] = v;
}

// K0c: pw1T[k*64+c] = pw1[c*128+k]  (after k_cvt)
__global__ void k_trans(float* __restrict__ ws){
  int i = blockIdx.x * blockDim.x + threadIdx.x;
  if (i < 8192){
    int k = i >> 6, c = i & 63;
    ws[OFW_PW1T + i] = ws[OFW_PW1 + c * 128 + k];
  }
}

// K1: x_drop = drop_mask[:,None] * x  -> fp32 (4 elems/thread)
__global__ void k_xdrop(const void* __restrict__ xr, const void* __restrict__ dmr,
                        const float* __restrict__ flag, float* __restrict__ xd){
  int i4 = blockIdx.x * blockDim.x + threadIdx.x;
  if (i4 >= NN * 16) return;
  int n = i4 >> 4;
  float4 o;
  if (flag[0] > 0.5f){
    uint2 w = ((const uint2*)xr)[i4];
    float dv = __bfloat162float(((const __hip_bfloat16*)dmr)[n]);
    o.x = bflo(w.x) * dv; o.y = bfhi(w.x) * dv;
    o.z = bflo(w.y) * dv; o.w = bfhi(w.y) * dv;
  } else {
    float4 xv = ((const float4*)xr)[i4];
    float dv = ((const float*)dmr)[n];
    o.x = xv.x * dv; o.y = xv.y * dv; o.z = xv.z * dv; o.w = xv.w * dv;
  }
  ((float4*)xd)[i4] = o;
}

// ---- CSR build (col direction only; row-degree kept in cnt histogram) ----
__global__ void k_hist(const int* __restrict__ ei, int* __restrict__ cnt){
  int e = blockIdx.x * blockDim.x + threadIdx.x;
  if (e < NE){
    atomicAdd(&cnt[ei[e]], 1);            // row (for deg)
    atomicAdd(&cnt[NN + ei[NE + e]], 1);  // col (for CSR)
  }
}

__global__ __launch_bounds__(256) void k_scanA(const int* __restrict__ cnt,
                                               int* __restrict__ bsum){
  __shared__ int red[256];
  int b = blockIdx.x;          // 0..195
  int i = b * 256 + threadIdx.x;
  int v = (i < NN) ? cnt[NN + i] : 0;
  red[threadIdx.x] = v; __syncthreads();
#pragma unroll
  for (int sh = 128; sh > 0; sh >>= 1){
    if (threadIdx.x < sh) red[threadIdx.x] += red[threadIdx.x + sh];
    __syncthreads();
  }
  if (threadIdx.x == 0) bsum[b] = red[0];
}

__global__ __launch_bounds__(256) void k_scanB(int* __restrict__ bsum,
                                               int* __restrict__ coff){
  __shared__ int sh[256];
  int t = threadIdx.x;
  int v = (t < 196) ? bsum[t] : 0;
  sh[t] = v; __syncthreads();
  for (int o = 1; o < 256; o <<= 1){
    int x = (t >= o) ? sh[t - o] : 0;
    __syncthreads();
    sh[t] += x;
    __syncthreads();
  }
  if (t < 196) bsum[t] = sh[t] - v;   // exclusive
  if (t == 0) coff[NN] = NE;
}

__global__ __launch_bounds__(256) void k_scanC(const int* __restrict__ cnt,
                                               const int* __restrict__ bsum,
                                               int* __restrict__ coff){
  __shared__ int sh[256];
  int b = blockIdx.x, t = threadIdx.x;
  int i = b * 256 + t;
  int v = (i < NN) ? cnt[NN + i] : 0;
  sh[t] = v; __syncthreads();
  for (int o = 1; o < 256; o <<= 1){
    int x = (t >= o) ? sh[t - o] : 0;
    __syncthreads();
    sh[t] += x;
    __syncthreads();
  }
  int excl = sh[t] - v + bsum[b];
  if (i < NN) coff[i] = excl;
}

__global__ void k_fill(const int* __restrict__ ei, const int* __restrict__ coff,
                       int* __restrict__ cur, int* __restrict__ csrc){
  int e = blockIdx.x * blockDim.x + threadIdx.x;
  if (e < NE){
    int r = ei[e], c = ei[NE + e];
    int pc = coff[c] + atomicAdd(&cur[c], 1);
    csrc[pc] = r;
  }
}

// ---- lane-parallel CSR row-gather: sum_{e in [st,en)} table[idx[e]] (64-float rows)
__device__ inline float4 gather_rowsum(const int* __restrict__ idxarr, int st, int en,
                                       const float* __restrict__ table, int lane,
                                       int g, int sub){
  float4 a0 = {0,0,0,0}, a1 = {0,0,0,0}, a2 = {0,0,0,0}, a3 = {0,0,0,0};
  for (int bb = st; bb < en; bb += 64){
    int rem = en - bb;
    int myi = (bb + lane < en) ? idxarr[bb + lane] : 0;
    int niter = ((rem < 64 ? rem : 64) + 3) >> 2;
    int i = 0;
    for (; i + 4 <= niter; i += 4){
      int s0 = __shfl(myi, g + ((i    ) << 2), 64);
      int s1 = __shfl(myi, g + ((i + 1) << 2), 64);
      int s2 = __shfl(myi, g + ((i + 2) << 2), 64);
      int s3 = __shfl(myi, g + ((i + 3) << 2), 64);
      if ((g + (i << 2))       < rem){ float4 v = *(const float4*)(table + (s0 << 6) + (sub << 2)); a0.x += v.x; a0.y += v.y; a0.z += v.z; a0.w += v.w; }
      if ((g + ((i + 1) << 2)) < rem){ float4 v = *(const float4*)(table + (s1 << 6) + (sub << 2)); a1.x += v.x; a1.y += v.y; a1.z += v.z; a1.w += v.w; }
      if ((g + ((i + 2) << 2)) < rem){ float4 v = *(const float4*)(table + (s2 << 6) + (sub << 2)); a2.x += v.x; a2.y += v.y; a2.z += v.z; a2.w += v.w; }
      if ((g + ((i + 3) << 2)) < rem){ float4 v = *(const float4*)(table + (s3 << 6) + (sub << 2)); a3.x += v.x; a3.y += v.y; a3.z += v.z; a3.w += v.w; }
    }
    for (; i < niter; ++i){
      int slot = g + (i << 2);
      int s0 = __shfl(myi, slot, 64);
      if (slot < rem){ float4 v = *(const float4*)(table + (s0 << 6) + (sub << 2)); a0.x += v.x; a0.y += v.y; a0.z += v.z; a0.w += v.w; }
    }
  }
  float4 a;
  a.x = (a0.x + a1.x) + (a2.x + a3.x);
  a.y = (a0.y + a1.y) + (a2.y + a3.y);
  a.z = (a0.z + a1.z) + (a2.z + a3.z);
  a.w = (a0.w + a1.w) + (a2.w + a3.w);
  a.x += __shfl_xor(a.x, 16, 64); a.x += __shfl_xor(a.x, 32, 64);
  a.y += __shfl_xor(a.y, 16, 64); a.y += __shfl_xor(a.y, 32, 64);
  a.z += __shfl_xor(a.z, 16, 64); a.z += __shfl_xor(a.z, 32, 64);
  a.w += __shfl_xor(a.w, 16, 64); a.w += __shfl_xor(a.w, 32, 64);
  return a;
}

// K2: agg[n] = sum_{e: col=n} xd[csrc[e]]
__global__ __launch_bounds__(256) void k_agg2(const int* __restrict__ coff,
                                              const int* __restrict__ csrc,
                                              const float* __restrict__ xd,
                                              float* __restrict__ agg){
  int gid = blockIdx.x * 256 + threadIdx.x;
  int lane = gid & 63, wid = gid >> 6;
  int nw = (gridDim.x * 256) >> 6;
  int g = lane >> 4, sub = lane & 15;
  for (int n = wid; n < NN; n += nw){
    int st = coff[n], en = coff[n + 1];
    float4 a = gather_rowsum(csrc, st, en, xd, lane, g, sub);
    if (g == 0) *(float4*)(agg + (n << 6) + (sub << 2)) = a;
  }
}

// K3: x1 = relu(agg @ W1_rel^T + b1 + x_drop @ W1_root^T), 8-node batches
__global__ __launch_bounds__(128) void k_x1(const float* __restrict__ agg,
                                            const float* __restrict__ xd,
                                            const float* __restrict__ wts,
                                            float* __restrict__ x1){
  __shared__ float nb[8][2][64];
  int t = threadIdx.x;
  float wr[64], wo[64];
#pragma unroll
  for (int j = 0; j < 64; ++j){
    wr[j] = wts[OFW_W1R + t * 64 + j];
    wo[j] = wts[OFW_W1O + t * 64 + j];
  }
  float bias = wts[OFW_B1 + t];
  const int nbatch = NN / 8;   // 6250
  for (int b = blockIdx.x; b < nbatch; b += gridDim.x){
    int base = b * 8;
#pragma unroll
    for (int i = 0; i < 2; ++i){
      int f = t + (i << 7);
      int u = f >> 5;
      int j = f & 31;
      const float* src = (j < 16) ? (agg + ((base + u) << 6) + (j << 2))
                                  : (xd  + ((base + u) << 6) + ((j - 16) << 2));
      *(float4*)&nb[u][j >> 4][(j & 15) << 2] = *(const float4*)src;
    }
    __syncthreads();
#pragma unroll
    for (int u = 0; u < 8; ++u){
      float acc_a = bias, acc_x = 0.0f;
#pragma unroll
      for (int j = 0; j < 16; ++j){
        float4 va = *(const float4*)&nb[u][0][j << 2];
        float4 vx = *(const float4*)&nb[u][1][j << 2];
        acc_a += va.x * wr[4*j] + va.y * wr[4*j+1] + va.z * wr[4*j+2] + va.w * wr[4*j+3];
        acc_x += vx.x * wo[4*j] + vx.y * wo[4*j+1] + vx.z * wo[4*j+2] + vx.w * wo[4*j+3];
      }
      x1[(base + u) * HC + t] = fmaxf(acc_a + acc_x, 0.0f);
    }
    __syncthreads();
  }
}

// K4: fused s1 = LN(x1 @ pW1^T + pb1) -> softmax/log_softmax, per-64-node tile.
__global__ __launch_bounds__(256) void k_s1f(const float* __restrict__ x1,
                                             const float* __restrict__ wts,
                                             const int* __restrict__ cnt,
                                             float* __restrict__ s,
                                             void* __restrict__ outp,
                                             const float* __restrict__ flag,
                                             float* __restrict__ scal){
  __shared__ float xs[64 * 129];     // x1 tile, then logit tile (stride 129)
  __shared__ float pwsh[HC * 64];    // [k][c]
  __shared__ float gsh[64], bsh[64];
  __shared__ float wden[4];
  int t = threadIdx.x;
  int base = blockIdx.x * 64;
  for (int i = t; i < HC * 64; i += 256) pwsh[i] = wts[OFW_PW1T + i];
  if (t < 64){ gsh[t] = wts[OFW_G1 + t]; bsh[t] = wts[OFW_BE1 + t]; }
  for (int f = t; f < 64 * 32; f += 256){
    int r = f >> 5, kq = f & 31;
    float4 v = (base + r < NN) ? *(const float4*)(x1 + (base + r) * HC + (kq << 2))
                               : make_float4(0, 0, 0, 0);
    xs[r * 129 + 4*kq]     = v.x;
    xs[r * 129 + 4*kq + 1] = v.y;
    xs[r * 129 + 4*kq + 2] = v.z;
    xs[r * 129 + 4*kq + 3] = v.w;
  }
  __syncthreads();
  int ni = t >> 4, cj = t & 15;
  float4 c0 = {0,0,0,0}, c1 = {0,0,0,0}, c2 = {0,0,0,0}, c3 = {0,0,0,0};
#pragma unroll 4
  for (int k = 0; k < HC; ++k){
    float4 b = *(const float4*)&pwsh[k * 64 + (cj << 2)];
    float a0 = xs[(ni * 4 + 0) * 129 + k];
    float a1 = xs[(ni * 4 + 1) * 129 + k];
    float a2 = xs[(ni * 4 + 2) * 129 + k];
    float a3 = xs[(ni * 4 + 3) * 129 + k];
    c0.x += a0 * b.x; c0.y += a0 * b.y; c0.z += a0 * b.z; c0.w += a0 * b.w;
    c1.x += a1 * b.x; c1.y += a1 * b.y; c1.z += a1 * b.z; c1.w += a1 * b.w;
    c2.x += a2 * b.x; c2.y += a2 * b.y; c2.z += a2 * b.z; c2.w += a2 * b.w;
    c3.x += a3 * b.x; c3.y += a3 * b.y; c3.z += a3 * b.z; c3.w += a3 * b.w;
  }
  float4 pb = *(const float4*)&wts[OFW_PB1 + (cj << 2)];
  c0.x += pb.x; c0.y += pb.y; c0.z += pb.z; c0.w += pb.w;
  c1.x += pb.x; c1.y += pb.y; c1.z += pb.z; c1.w += pb.w;
  c2.x += pb.x; c2.y += pb.y; c2.z += pb.z; c2.w += pb.w;
  c3.x += pb.x; c3.y += pb.y; c3.z += pb.z; c3.w += pb.w;
  __syncthreads();   // all xs reads done; now overwrite with logits
  {
    int col = cj << 2;
    float* r0 = &xs[(ni * 4 + 0) * 129 + col];
    float* r1 = &xs[(ni * 4 + 1) * 129 + col];
    float* r2 = &xs[(ni * 4 + 2) * 129 + col];
    float* r3 = &xs[(ni * 4 + 3) * 129 + col];
    r0[0] = c0.x; r0[1] = c0.y; r0[2] = c0.z; r0[3] = c0.w;
    r1[0] = c1.x; r1[1] = c1.y; r1[2] = c1.z; r1[3] = c1.w;
    r2[0] = c2.x; r2[1] = c2.y; r2[2] = c2.z; r2[3] = c2.w;
    r3[0] = c3.x; r3[1] = c3.y; r3[2] = c3.z; r3[3] = c3.w;
  }
  __syncthreads();
  bool bf = flag[0] > 0.5f;
  int lane = t & 63, wv = t >> 6;
  float dacc = 0.0f;
  for (int rr = 0; rr < 16; ++rr){
    int row = wv * 16 + rr;
    int n = base + row;
    if (n >= NN) break;
    float z = xs[row * 129 + lane];
    float mu  = wave_sum(z) * (1.0f / 64.0f);
    float d   = z - mu;
    float var = wave_sum(d * d) * (1.0f / 64.0f);
    float y   = d * rsqrtf(var + 1e-5f) * gsh[lane] + bsh[lane];
    float m   = wave_max(y);
    float ex  = expf(y - m);
    float se  = wave_sum(ex);
    float sv  = ex / se;
    s[n * 64 + lane] = sv;
    store_out(outp, 4LL + (long long)n * 64 + lane, (y - m) - logf(se), bf);
    dacc += (float)cnt[n] * sv * sv;
  }
  float wsum = wave_sum(dacc);
  if (lane == 0) wden[wv] = wsum;
  __syncthreads();
  if (t == 0) atomicAdd(&scal[0], wden[0] + wden[1] + wden[2] + wden[3]);
}

// K5: padj partials via col-CSR: padj = sum_n asCol[n] (x) s[n]
__global__ __launch_bounds__(256) void k_padj2(const int* __restrict__ coff,
                                               const int* __restrict__ csrc,
                                               const float* __restrict__ s,
                                               float* __restrict__ padjp){
  __shared__ float rs[16 * 64];   // i-side (gathered asCol)
  __shared__ float ra[16 * 64];   // j-side (s[n])
  int t = threadIdx.x, lane = t & 63, w = t >> 6;
  int g = lane >> 4, sub = lane & 15;
  int i4 = t >> 4;
  int j4 = t & 15;
  float4 acc0 = {0,0,0,0}, acc1 = {0,0,0,0}, acc2 = {0,0,0,0}, acc3 = {0,0,0,0};
  const int nbatch = NN / 16;   // 3125
  for (int b = blockIdx.x; b < nbatch; b += gridDim.x){
    int base = b * 16;
#pragma unroll
    for (int q = 0; q < 4; ++q){
      int k = w * 4 + q;
      int n = base + k;
      int st = coff[n], en = coff[n + 1];
      float4 a = gather_rowsum(csrc, st, en, s, lane, g, sub);
      if (g == 0){
        *(float4*)&rs[k * 64 + (sub << 2)] = a;
      } else if (g == 1){
        *(float4*)&ra[k * 64 + (sub << 2)] = *(const float4*)(s + (n << 6) + (sub << 2));
      }
    }
    __syncthreads();
#pragma unroll
    for (int k = 0; k < 16; ++k){
      float4 a  = *(const float4*)&rs[k * 64 + (i4 << 2)];
      float4 bv = *(const float4*)&ra[k * 64 + (j4 << 2)];
      acc0.x += a.x * bv.x; acc0.y += a.x * bv.y; acc0.z += a.x * bv.z; acc0.w += a.x * bv.w;
      acc1.x += a.y * bv.x; acc1.y += a.y * bv.y; acc1.z += a.y * bv.z; acc1.w += a.y * bv.w;
      acc2.x += a.z * bv.x; acc2.y += a.z * bv.y; acc2.z += a.z * bv.z; acc2.w += a.z * bv.w;
      acc3.x += a.w * bv.x; acc3.y += a.w * bv.y; acc3.z += a.w * bv.z; acc3.w += a.w * bv.w;
    }
    __syncthreads();
  }
  float* pp = padjp + blockIdx.x * 4096;
  *(float4*)&pp[(i4 * 4 + 0) * 64 + (j4 << 2)] = acc0;
  *(float4*)&pp[(i4 * 4 + 1) * 64 + (j4 << 2)] = acc1;
  *(float4*)&pp[(i4 * 4 + 2) * 64 + (j4 << 2)] = acc2;
  *(float4*)&pp[(i4 * 4 + 3) * 64 + (j4 << 2)] = acc3;
}

// K6: px/sts partials. 1024-thread blocks (16 waves/CU), 32-node batches.
// thread t: cluster c=t>>4, quad q=t&15; owns px cols {4q..4q+3, 4(q+16)..} and sts {4q..}.
__global__ __launch_bounds__(1024) void k_pool(const float* __restrict__ s,
                                               const float* __restrict__ x1,
                                               float* __restrict__ part){
  __shared__ float ssh[32 * 64];    // 8 KB
  __shared__ float xsh[32 * 128];   // 16 KB
  int t = threadIdx.x;
  int c = t >> 4, q = t & 15;
  float4 apx0 = {0,0,0,0}, apx1 = {0,0,0,0}, ast0 = {0,0,0,0};
  const int nbatch = (NN + 31) / 32;   // 1563
  for (int b = blockIdx.x; b < nbatch; b += gridDim.x){
    int base = b * 32;
    int kmax = NN - base; if (kmax > 32) kmax = 32;
    // stage s: 512 float4 (threads 0..511)
    if (t < 512){
      int k = t >> 4, col = t & 15;
      float4 v = (k < kmax) ? *(const float4*)(s + ((base + k) << 6) + (col << 2))
                            : make_float4(0, 0, 0, 0);
      *(float4*)&ssh[k * 64 + (col << 2)] = v;
    }
    // stage x1: 1024 float4, one per thread
    {
      int k = t >> 5, col = t & 31;
      float4 v = (k < kmax) ? *(const float4*)(x1 + (base + k) * HC + (col << 2))
                            : make_float4(0, 0, 0, 0);
      *(float4*)&xsh[k * 128 + (col << 2)] = v;
    }
    __syncthreads();
    for (int k = 0; k < kmax; ++k){
      float sv = ssh[k * 64 + c];
      float4 xv0 = *(const float4*)&xsh[k * 128 + (q << 2)];
      float4 xv1 = *(const float4*)&xsh[k * 128 + ((q + 16) << 2)];
      float4 s0  = *(const float4*)&ssh[k * 64 + (q << 2)];
      apx0.x += sv * xv0.x; apx0.y += sv * xv0.y; apx0.z += sv * xv0.z; apx0.w += sv * xv0.w;
      apx1.x += sv * xv1.x; apx1.y += sv * xv1.y; apx1.z += sv * xv1.z; apx1.w += sv * xv1.w;
      ast0.x += sv * s0.x;  ast0.y += sv * s0.y;  ast0.z += sv * s0.z;  ast0.w += sv * s0.w;
    }
    __syncthreads();
  }
  float* pp = part + blockIdx.x * 12288;
  *(float4*)&pp[c * 128 + (q << 2)]        = apx0;
  *(float4*)&pp[c * 128 + ((q + 16) << 2)] = apx1;
  *(float4*)&pp[8192 + c * 64 + (q << 2)]  = ast0;
}

// K6b: reduce partials -> px, sts (192 blocks) and padj (64 blocks). grid=256.
__global__ __launch_bounds__(256) void k_red(const float* __restrict__ pxstsp,
                                             const float* __restrict__ padjp,
                                             float* __restrict__ px,
                                             float* __restrict__ sts,
                                             float* __restrict__ padj){
  __shared__ float sh[256];
  int b = blockIdx.x, t = threadIdx.x;
  int ci = t & 63, pc = t >> 6;
  if (b < 192){
    int cell = b * 64 + ci;
    float a0 = 0, a1 = 0, a2 = 0, a3 = 0;
    const float* basep = pxstsp + cell;
    int p0 = pc * (P_POOL / 4);
    for (int p = 0; p < P_POOL / 4; p += 4){
      a0 += basep[(p0 + p    ) * 12288];
      a1 += basep[(p0 + p + 1) * 12288];
      a2 += basep[(p0 + p + 2) * 12288];
      a3 += basep[(p0 + p + 3) * 12288];
    }
    sh[t] = (a0 + a1) + (a2 + a3);
    __syncthreads();
    if (t < 64){
      float r = sh[t] + sh[t + 64] + sh[t + 128] + sh[t + 192];
      int cell2 = b * 64 + t;
      if (cell2 < 8192) px[cell2] = r; else sts[cell2 - 8192] = r;
    }
  } else {
    int cell = (b - 192) * 64 + ci;
    float a0 = 0, a1 = 0, a2 = 0, a3 = 0;
    const float* basep = padjp + cell;
    int p0 = pc * (P_PADJ / 4);
    for (int p = 0; p < P_PADJ / 4; p += 4){
      a0 += basep[(p0 + p    ) * 4096];
      a1 += basep[(p0 + p + 1) * 4096];
      a2 += basep[(p0 + p + 2) * 4096];
      a3 += basep[(p0 + p + 3) * 4096];
    }
    sh[t] = (a0 + a1) + (a2 + a3);
    __syncthreads();
    if (t < 64) padj[(b - 192) * 64 + t] = sh[t] + sh[t + 64] + sh[t + 128] + sh[t + 192];
  }
}

// K7a: M, Mt, deg2, num1(trace), o1
__global__ __launch_bounds__(256) void k_m(const float* __restrict__ padj,
                                           const float* __restrict__ sts,
                                           float* __restrict__ Mg,
                                           float* __restrict__ Mtg,
                                           float* __restrict__ deg2,
                                           float* __restrict__ scal){
  __shared__ float red[256];
  __shared__ float psh[4096];
  __shared__ float dsi[64];
  int t = threadIdx.x;
  const float TH = 1.0f / 63.0f;
  for (int i = t; i < 4096; i += 256) psh[i] = padj[i];
  __syncthreads();
  float v = (t < 64) ? psh[t * 65] : 0.0f;
  float num1 = block_reduce_256(v, red, t);
  v = 0.0f;
  for (int i = t; i < 4096; i += 256){ float e = sts[i]; v += e * e; }
  float nrm1 = sqrtf(block_reduce_256(v, red, t));
  v = 0.0f;
  for (int i = t; i < 4096; i += 256){
    float e = sts[i] / (nrm1 + 1e-10f) - ((i % 65 == 0) ? 0.125f : 0.0f);
    v += e * e;
  }
  float o1 = sqrtf(block_reduce_256(v, red, t));
  if (t < 64){
    float rs = 0.0f;
    for (int j = 0; j < 64; ++j) rs += (j == t) ? 0.0f : psh[t * 64 + j];
    dsi[t] = 1.0f / (sqrtf(rs) + 1e-15f);
  }
  __syncthreads();
  for (int i = t; i < 4096; i += 256){
    int r = i >> 6, c = i & 63;
    float a = (r == c) ? 0.0f : psh[i];
    float m = (a * dsi[r] * dsi[c] > TH) ? 1.0f : 0.0f;
    Mg[i] = m;
    Mtg[c * 64 + r] = m;
  }
  __syncthreads();
  for (int i = t; i < 4096; i += 256){
    int r = i >> 6, c = i & 63;
    float a = (r == c) ? 0.0f : psh[i];
    psh[i] = (a * dsi[r] * dsi[c] > TH) ? 1.0f : 0.0f;
  }
  __syncthreads();
  if (t < 64){
    float d2 = 0.0f;
    for (int j = 0; j < 64; ++j) d2 += psh[t * 64 + j];
    deg2[t] = d2;
  }
  if (t == 0){ scal[1] = num1; scal[2] = o1; }
}

// K7b: per-cluster fused mp/x2/s2-logits/LN/softmax (64 blocks x 128 thr)
__global__ __launch_bounds__(128) void k_x2(const float* __restrict__ Mtg,
                                            const float* __restrict__ px,
                                            const float* __restrict__ wts,
                                            float* __restrict__ s2g,
                                            void* __restrict__ out,
                                            const float* __restrict__ flag){
  __shared__ float mt[64], pxc[128], mpsh[128], x2sh[128];
  __shared__ float part[16][9], lsh[16], stat[2];
  int c = blockIdx.x, t = threadIdx.x;
  if (t < 64) mt[t] = Mtg[c * 64 + t];
  pxc[t] = px[c * 128 + t];
  __syncthreads();
  float mp = 0.0f;
  for (int i = 0; i < 64; ++i) mp += mt[i] * px[i * 128 + t];
  mpsh[t] = mp;
  __syncthreads();
  float acc = wts[OFW_B2 + t];
  const float* wrr = wts + OFW_W2R + t * 128;
  const float* wor = wts + OFW_W2O + t * 128;
  for (int k = 0; k < 128; ++k) acc += mpsh[k] * wrr[k] + pxc[k] * wor[k];
  x2sh[t] = fmaxf(acc, 0.0f);
  __syncthreads();
  { int u = t >> 3, p = t & 7;
    const float* pw = wts + OFW_PW2 + u * 128 + p * 16;
    float pa = 0.0f;
    for (int k = 0; k < 16; ++k) pa += x2sh[p * 16 + k] * pw[k];
    part[u][p] = pa;
  }
  __syncthreads();
  if (t < 16){
    float l = wts[OFW_PB2 + t];
    for (int p = 0; p < 8; ++p) l += part[t][p];
    lsh[t] = l;
  }
  __syncthreads();
  if (t == 0){
    float mu = 0.0f;
    for (int u = 0; u < 16; ++u) mu += lsh[u];
    mu *= (1.0f / 16.0f);
    float var = 0.0f;
    for (int u = 0; u < 16; ++u){ float d = lsh[u] - mu; var += d * d; }
    var *= (1.0f / 16.0f);
    float rstd = rsqrtf(var + 1e-5f);
    float m = -3.4e38f;
    for (int u = 0; u < 16; ++u){
      lsh[u] = (lsh[u] - mu) * rstd * wts[OFW_G2 + u] + wts[OFW_BE2 + u];
      m = fmaxf(m, lsh[u]);
    }
    float se = 0.0f;
    for (int u = 0; u < 16; ++u) se += expf(lsh[u] - m);
    stat[0] = m; stat[1] = logf(se);
  }
  __syncthreads();
  if (t < 16){
    float ls = (lsh[t] - stat[0]) - stat[1];
    store_out(out, 4LL + (long long)NN * NC1 + c * 16 + t, ls, flag[0] > 0.5f);
    s2g[c * 16 + t] = expf(ls);
  }
}

// K7c: mc2 / o2 tail (1 block)
__global__ __launch_bounds__(256) void k_tail(const float* __restrict__ Mg,
                                              const float* __restrict__ s2g,
                                              const float* __restrict__ deg2,
                                              const float* __restrict__ scal,
                                              void* __restrict__ out,
                                              const float* __restrict__ flag){
  __shared__ float red[256];
  __shared__ float Msh[4096];
  __shared__ float s2sh[1024];
  __shared__ float d2sh[64];
  __shared__ float sts2[256];
  int t = threadIdx.x;
  for (int i = t; i < 4096; i += 256) Msh[i] = Mg[i];
  for (int i = t; i < 1024; i += 256) s2sh[i] = s2g[i];
  if (t < 64) d2sh[t] = deg2[t];
  __syncthreads();
  float vnum = 0.0f, vden = 0.0f;
  for (int m = 0; m < 4; ++m){
    int id = t + m * 256;
    int c = id >> 4, u = id & 15;
    float a = 0.0f;
    for (int j = 0; j < 64; ++j) a += Msh[c * 64 + j] * s2sh[j * 16 + u];
    float sv = s2sh[id];
    vnum += sv * a;
    vden += d2sh[c] * sv * sv;
  }
  float num2 = block_reduce_256(vnum, red, t);
  float den2 = block_reduce_256(vden, red, t) + 1e-10f;
  { int u = t >> 4, w = t & 15;
    float a = 0.0f;
    for (int c2 = 0; c2 < 64; ++c2) a += s2sh[c2 * 16 + u] * s2sh[c2 * 16 + w];
    sts2[t] = a;
  }
  __syncthreads();
  float v = sts2[t] * sts2[t];
  float nrm2 = sqrtf(block_reduce_256(v, red, t));
  { float e = sts2[t] / (nrm2 + 1e-10f) - (((t >> 4) == (t & 15)) ? 0.25f : 0.0f);
    v = e * e; }
  float o2 = sqrtf(block_reduce_256(v, red, t));
  if (t == 0){
    bool bf = flag[0] > 0.5f;
    float den = scal[0] + 1e-10f;
    store_out(out, 0, -scal[1] / den, bf);
    store_out(out, 1, scal[2], bf);
    store_out(out, 2, -num2 / den2, bf);
    store_out(out, 3, o2, bf);
  }
}

extern "C" void kernel_launch(void* const* d_in, const int* in_sizes, int n_in,
                              void* d_out, int out_size, void* d_ws, size_t ws_size,
                              hipStream_t stream){
  const void* x  = d_in[0];
  const int*  ei = (const int*)d_in[1];
  const void* dm = d_in[2];

  float* ws    = (float*)d_ws;
  float* flag  = ws + OFF_FLAG;
  float* xd    = ws + OFF_XD;
  float* x1    = ws + OFF_X1;
  float* s     = ws + OFF_S;
  float* agg   = ws + OFF_AGG;
  float* px    = ws + OFF_PX;
  float* padj  = ws + OFF_PADJ;
  float* sts   = ws + OFF_STS;
  float* scal  = ws + OFF_SCAL;
  float* Mg    = ws + OFF_MG;
  float* Mtg   = ws + OFF_MTG;
  float* deg2  = ws + OFF_DEG2;
  float* s2g   = ws + OFF_S2G;
  float* pxstsp= ws + OFF_PXSTSP;
  float* padjp = ws + OFF_PADJP;
  int* coff = (int*)(ws + OFF_COFF);
  int* bsum = (int*)(ws + OFF_BSUM);
  int* csrc = (int*)(ws + OFF_CSRC);
  int* cnt  = (int*)(ws + OFF_CNT);
  int* cur  = (int*)(ws + OFF_CUR);

  hipMemsetAsync(ws + OFF_SCAL, 0, (size_t)ZERO_FLOATS * sizeof(float), stream);

  k_detect<<<1, 256, 0, stream>>>((const unsigned int*)dm, flag);
  k_cvt<<<(CVT_TOTAL + 255) / 256, 256, 0, stream>>>(
      d_in[3], d_in[5], d_in[4], d_in[6], d_in[7], d_in[8], d_in[9],
      d_in[10], d_in[11], d_in[12], d_in[13], d_in[14], d_in[15], d_in[16],
      flag, ws);
  k_trans<<<32, 256, 0, stream>>>(ws);
  k_xdrop<<<(NN * 16 + 255) / 256, 256, 0, stream>>>(x, dm, flag, xd);
  k_hist<<<(NE + 255) / 256, 256, 0, stream>>>(ei, cnt);
  k_scanA<<<196, 256, 0, stream>>>(cnt, bsum);
  k_scanB<<<1, 256, 0, stream>>>(bsum, coff);
  k_scanC<<<196, 256, 0, stream>>>(cnt, bsum, coff);
  k_fill<<<(NE + 255) / 256, 256, 0, stream>>>(ei, coff, cur, csrc);
  k_agg2<<<2048, 256, 0, stream>>>(coff, csrc, xd, agg);
  k_x1<<<2048, 128, 0, stream>>>(agg, xd, ws, x1);
  k_s1f<<<(NN + 63) / 64, 256, 0, stream>>>(x1, ws, cnt, s, d_out, flag, scal);
  k_pool<<<P_POOL, 1024, 0, stream>>>(s, x1, pxstsp);
  k_padj2<<<P_PADJ, 256, 0, stream>>>(coff, csrc, s, padjp);
  k_red<<<256, 256, 0, stream>>>(pxstsp, padjp, px, sts, padj);
  k_m<<<1, 256, 0, stream>>>(padj, sts, Mg, Mtg, deg2, scal);
  k_x2<<<64, 128, 0, stream>>>(Mtg, px, ws, s2g, d_out, flag);
  k_tail<<<1, 256, 0, stream>>>(Mg, s2g, deg2, scal, d_out, flag);
}